// Round 2
// baseline (1211.688 us; speedup 1.0000x reference)
//
#include <hip/hip_runtime.h>
#include <hip/hip_bf16.h>

#define LL 4096
#define DD 192
#define NN 16

// ---------------------------------------------------------------------------
// K1: x_dbl projection. One thread per (b,k,l). Computes 38 dot-products over
// D=192. xs[k>=2][l] == xs[k-2][L-1-l], so k>=2 blocks read the same gather
// pattern and write to reversed scan positions. Weights are block-uniform
// (k from blockIdx) -> scalar-load codegen expected.
// ---------------------------------------------------------------------------
__global__ __launch_bounds__(256) void k_proj(
    const float* __restrict__ x, const float* __restrict__ Wp,
    float* __restrict__ dtr, float* __restrict__ Bsv, float* __restrict__ Csv)
{
  const int tid = threadIdx.x;
  const int l = blockIdx.x * 256 + tid;
  const int k = blockIdx.y;
  const int b = blockIdx.z;
  // scan-order position l -> flat position in x's (h,w) for the gather
  const int pos = (k & 1) ? (((l & 63) << 6) | (l >> 6)) : l;
  const float* __restrict__ xrow = x + (size_t)b * DD * LL + pos;

  float acc[38];
#pragma unroll
  for (int c = 0; c < 38; ++c) acc[c] = 0.f;

  const float* __restrict__ wk = Wp + k * 38 * DD;

  float xn0 = xrow[0 * LL], xn1 = xrow[1 * LL], xn2 = xrow[2 * LL], xn3 = xrow[3 * LL];
  for (int d0 = 0; d0 < DD; d0 += 4) {
    const float x0 = xn0, x1 = xn1, x2 = xn2, x3 = xn3;
    if (d0 + 4 < DD) {   // prefetch next 4 channels
      xn0 = xrow[(size_t)(d0 + 4) * LL];
      xn1 = xrow[(size_t)(d0 + 5) * LL];
      xn2 = xrow[(size_t)(d0 + 6) * LL];
      xn3 = xrow[(size_t)(d0 + 7) * LL];
    }
#pragma unroll
    for (int c = 0; c < 38; ++c) {
      const float* __restrict__ wr = wk + c * DD + d0;
      float a = acc[c];
      a = fmaf(x0, wr[0], a);
      a = fmaf(x1, wr[1], a);
      a = fmaf(x2, wr[2], a);
      a = fmaf(x3, wr[3], a);
      acc[c] = a;
    }
  }

  const int ls = (k < 2) ? l : (LL - 1 - l);   // scan-order write position
  const size_t bk4 = (size_t)b * 4 + k;
  float* __restrict__ dr = dtr + (bk4 * LL + ls) * 8;   // 8-stride row, 6 used
  *(float4*)(dr)     = make_float4(acc[0], acc[1], acc[2], acc[3]);
  *(float2*)(dr + 4) = make_float2(acc[4], acc[5]);
  float* __restrict__ br = Bsv + (bk4 * LL + ls) * NN;
  *(float4*)(br + 0)  = make_float4(acc[6],  acc[7],  acc[8],  acc[9]);
  *(float4*)(br + 4)  = make_float4(acc[10], acc[11], acc[12], acc[13]);
  *(float4*)(br + 8)  = make_float4(acc[14], acc[15], acc[16], acc[17]);
  *(float4*)(br + 12) = make_float4(acc[18], acc[19], acc[20], acc[21]);
  float* __restrict__ cr = Csv + (bk4 * LL + ls) * NN;
  *(float4*)(cr + 0)  = make_float4(acc[22], acc[23], acc[24], acc[25]);
  *(float4*)(cr + 4)  = make_float4(acc[26], acc[27], acc[28], acc[29]);
  *(float4*)(cr + 8)  = make_float4(acc[30], acc[31], acc[32], acc[33]);
  *(float4*)(cr + 12) = make_float4(acc[34], acc[35], acc[36], acc[37]);
}

// ---------------------------------------------------------------------------
// K2: fused dt-projection + softplus + selective scan. 16 lanes per (b,k,d)
// chain, one state n per lane, h in one VGPR. Per 8-step block: lanes 0..7
// compute softplus(dtr.Wdt+bias) for step j=n, lanes 8..15 gather u=x[pos(k,l)]
// for step j=n-8; two width-16 shfl broadcasts feed everyone. dA exps are off
// the h critical chain (1 fma/step). Next block's raw loads are prefetched.
// y out via 4-stage shfl_xor quarter-wave reduce, stored bf16 (lane n==0;
// 4 groups/wave -> 4 consecutive d -> one 8B transaction).
// Blocks XCD-swizzled so the 12 blocks sharing (b,k) B/C slices stay in one L2.
// ---------------------------------------------------------------------------
__global__ __launch_bounds__(256) void k_scan(
    const float* __restrict__ x,    const float* __restrict__ dtr,
    const float* __restrict__ dtw,  const float* __restrict__ dtb,
    const float* __restrict__ Bsv,  const float* __restrict__ Csv,
    const float* __restrict__ Alog, __hip_bfloat16* __restrict__ ys)
{
  const int tid = threadIdx.x;
  const int g  = tid >> 4;                // chain group within block
  const int n  = tid & 15;                // state / role lane
  const int xcd = blockIdx.x & 7;
  const int t   = blockIdx.x >> 3;        // 0..47
  const int bk  = xcd * 4 + t / 12;       // 0..31, clustered per XCD
  const int dg  = t % 12;
  const int k   = bk & 3;
  const int b   = bk >> 2;
  const int d   = dg * 16 + g;
  const int kd  = k * DD + d;

  const float An = -__expf(Alog[(size_t)kd * NN + n]);
  const float w0 = dtw[kd*6+0], w1 = dtw[kd*6+1], w2 = dtw[kd*6+2],
              w3 = dtw[kd*6+3], w4 = dtw[kd*6+4], w5 = dtw[kd*6+5];
  const float bias = dtb[kd];

  const float* __restrict__ dtrp = dtr + (size_t)bk * LL * 8;
  const float* __restrict__ Bp   = Bsv + (size_t)bk * LL * NN + n;
  const float* __restrict__ Cp   = Csv + (size_t)bk * LL * NN + n;
  const float* __restrict__ xrow = x + ((size_t)b * DD + d) * LL;
  __hip_bfloat16* __restrict__ yp = ys + (size_t)bk * LL * DD + d;

  const int jrole = n & 7;
  const bool is_u = (n >= 8);

  float h = 0.f;
  float4 r0c = {0,0,0,0}; float2 r1c = {0,0}; float uc = 0.f;
  float Bc[8], Cc[8];
  {
    const int l = jrole;
    if (!is_u) {
      r0c = *(const float4*)(dtrp + (size_t)l * 8);
      r1c = *(const float2*)(dtrp + (size_t)l * 8 + 4);
    } else {
      int pp;
      if      (k == 0) pp = l;
      else if (k == 1) pp = ((l & 63) << 6) | (l >> 6);
      else if (k == 2) pp = LL - 1 - l;
      else { int t2 = LL - 1 - l; pp = ((t2 & 63) << 6) | (t2 >> 6); }
      uc = xrow[pp];
    }
#pragma unroll
    for (int j = 0; j < 8; ++j) { Bc[j] = Bp[j * NN]; Cc[j] = Cp[j * NN]; }
  }

  for (int lb = 0; lb < 512; ++lb) {
    // ---- prefetch raw data for next 8-step block ----
    float4 r0n = {0,0,0,0}; float2 r1n = {0,0}; float un = 0.f;
    float Bn[8], Cn[8];
    if (lb < 511) {
      const int l = (lb + 1) * 8 + jrole;
      if (!is_u) {
        r0n = *(const float4*)(dtrp + (size_t)l * 8);
        r1n = *(const float2*)(dtrp + (size_t)l * 8 + 4);
      } else {
        int pp;
        if      (k == 0) pp = l;
        else if (k == 1) pp = ((l & 63) << 6) | (l >> 6);
        else if (k == 2) pp = LL - 1 - l;
        else { int t2 = LL - 1 - l; pp = ((t2 & 63) << 6) | (t2 >> 6); }
        un = xrow[pp];
      }
      const float* __restrict__ bq = Bp + (size_t)(lb + 1) * 8 * NN;
      const float* __restrict__ cq = Cp + (size_t)(lb + 1) * 8 * NN;
#pragma unroll
      for (int j = 0; j < 8; ++j) { Bn[j] = bq[j * NN]; Cn[j] = cq[j * NN]; }
    }

    // ---- dt for this block (lanes 0..7 produce; value garbage on u-lanes) ----
    float v = bias + r0c.x*w0 + r0c.y*w1 + r0c.z*w2 + r0c.w*w3 + r1c.x*w4 + r1c.y*w5;
    float spv = (v > 20.f) ? v : __logf(1.f + __expf(v));

    float sp[8], uu[8];
#pragma unroll
    for (int j = 0; j < 8; ++j) {
      sp[j] = __shfl(spv, j, 16);
      uu[j] = __shfl(uc, 8 + j, 16);
    }
    float dA[8], tt[8];
#pragma unroll
    for (int j = 0; j < 8; ++j) {
      dA[j] = __expf(sp[j] * An);
      tt[j] = sp[j] * uu[j] * Bc[j];
    }

    const int lbase = lb * 8;
#pragma unroll
    for (int j = 0; j < 8; ++j) {
      h = fmaf(h, dA[j], tt[j]);          // 1 fma/step critical chain
      float p = h * Cc[j];
      p += __shfl_xor(p, 1);
      p += __shfl_xor(p, 2);
      p += __shfl_xor(p, 4);
      p += __shfl_xor(p, 8);
      if (n == 0) yp[(size_t)(lbase + j) * DD] = __float2bfloat16(p);
    }

    if (lb < 511) {
      r0c = r0n; r1c = r1n; uc = un;
#pragma unroll
      for (int j = 0; j < 8; ++j) { Bc[j] = Bn[j]; Cc[j] = Cn[j]; }
    }
  }
}

// ---------------------------------------------------------------------------
// K3: cross-merge + D-skip + LayerNorm(192) + channel-last store.
// 64-thread blocks, 3 channels per lane -> full 192-sum is one in-wave
// butterfly (no LDS, no barriers). All four directions' u at an output pos
// equal x[b,d,pos], so skip term is x * sum_k Ds.
// ---------------------------------------------------------------------------
__global__ __launch_bounds__(64) void k_merge(
    const __hip_bfloat16* __restrict__ ys, const float* __restrict__ x,
    const float* __restrict__ Ds, const float* __restrict__ nw,
    const float* __restrict__ nb, float* __restrict__ out)
{
  const int lane = threadIdx.x;
  const int b = blockIdx.y;
  const int p0 = blockIdx.x * 16;

  float Dsum[3], nwv[3], nbv[3];
#pragma unroll
  for (int i = 0; i < 3; ++i) {
    int d = lane + 64 * i;
    Dsum[i] = Ds[d] + Ds[DD + d] + Ds[2 * DD + d] + Ds[3 * DD + d];
    nwv[i] = nw[d];
    nbv[i] = nb[d];
  }
  const __hip_bfloat16* __restrict__ ysb = ys + (size_t)b * 4 * LL * DD;
  const float* __restrict__ xb  = x  + (size_t)b * DD * LL;
  float* __restrict__ ob = out + (size_t)b * LL * DD;

  for (int chk = 0; chk < 2; ++chk) {
    const int q0 = p0 + chk * 8;
    float v[8][3];
    float xr[8][3];
#pragma unroll
    for (int i = 0; i < 3; ++i) {
      const float* __restrict__ xrow = xb + (size_t)(lane + 64 * i) * LL + q0;
      float4 x0 = *(const float4*)(xrow);
      float4 x1 = *(const float4*)(xrow + 4);
      xr[0][i]=x0.x; xr[1][i]=x0.y; xr[2][i]=x0.z; xr[3][i]=x0.w;
      xr[4][i]=x1.x; xr[5][i]=x1.y; xr[6][i]=x1.z; xr[7][i]=x1.w;
    }
#pragma unroll
    for (int j = 0; j < 8; ++j) {
      const int pos = q0 + j;
      const int tpos = ((pos & 63) << 6) | (pos >> 6);
#pragma unroll
      for (int i = 0; i < 3; ++i) {
        const int d = lane + 64 * i;
        float s = __bfloat162float(ysb[((size_t)0 * LL + pos) * DD + d])
                + __bfloat162float(ysb[((size_t)2 * LL + (LL - 1 - pos)) * DD + d])
                + __bfloat162float(ysb[((size_t)1 * LL + tpos) * DD + d])
                + __bfloat162float(ysb[((size_t)3 * LL + (LL - 1 - tpos)) * DD + d]);
        v[j][i] = s + xr[j][i] * Dsum[i];
      }
    }
#pragma unroll
    for (int j = 0; j < 8; ++j) {
      float s1 = v[j][0] + v[j][1] + v[j][2];
      float s2 = v[j][0]*v[j][0] + v[j][1]*v[j][1] + v[j][2]*v[j][2];
#pragma unroll
      for (int m = 1; m < 64; m <<= 1) {
        s1 += __shfl_xor(s1, m);
        s2 += __shfl_xor(s2, m);
      }
      const float mu  = s1 * (1.f / 192.f);
      const float var = s2 * (1.f / 192.f) - mu * mu;
      const float rs  = rsqrtf(var + 1e-5f);
      const int pos = q0 + j;
#pragma unroll
      for (int i = 0; i < 3; ++i) {
        ob[(size_t)pos * DD + lane + 64 * i] = (v[j][i] - mu) * rs * nwv[i] + nbv[i];
      }
    }
  }
}

// ---------------------------------------------------------------------------
// Workspace layout (float slots):
//   dtr  [B,4,L,8]  fp32    1,048,576
//   Bs   [B,4,L,16] fp32    2,097,152
//   Cs   [B,4,L,16] fp32    2,097,152
//   ys   [B,4,L,D]  bf16   12,582,912  (25,165,824 bf16 elems)
// total 17,825,792 float-slots = 71.3 MB  (was 323 MB -> suspected ws overflow)
// ---------------------------------------------------------------------------
extern "C" void kernel_launch(void* const* d_in, const int* in_sizes, int n_in,
                              void* d_out, int out_size, void* d_ws, size_t ws_size,
                              hipStream_t stream)
{
  (void)in_sizes; (void)n_in; (void)out_size; (void)ws_size;
  const float* x    = (const float*)d_in[0];
  const float* Wp   = (const float*)d_in[1];
  const float* dtw  = (const float*)d_in[2];
  const float* dtb  = (const float*)d_in[3];
  const float* Alog = (const float*)d_in[4];
  const float* Ds   = (const float*)d_in[5];
  const float* nw   = (const float*)d_in[6];
  const float* nb   = (const float*)d_in[7];
  float* out = (float*)d_out;
  float* ws  = (float*)d_ws;

  float* dtrw = ws;
  float* Bsv  = ws + 1048576;
  float* Csv  = ws + 3145728;
  __hip_bfloat16* ysv = (__hip_bfloat16*)(ws + 5242880);

  k_proj <<<dim3(16, 4, 8), 256, 0, stream>>>(x, Wp, dtrw, Bsv, Csv);
  k_scan <<<384,            256, 0, stream>>>(x, dtrw, dtw, dtb, Bsv, Csv, Alog, ysv);
  k_merge<<<dim3(256, 8),    64, 0, stream>>>(ysv, x, Ds, nw, nb, out);
}

// Round 3
// 482.229 us; speedup vs baseline: 2.5127x; 2.5127x over previous
//
#include <hip/hip_runtime.h>
#include <hip/hip_bf16.h>

#define LL 4096
#define DD 192
#define NN 16
#define NCH 32      // chunks for the 2-pass scan
#define LC  128     // steps per chunk = LL/NCH

// ---------------------------------------------------------------------------
// K1: x_dbl projection (unchanged from R2 — correct, not the bottleneck).
// One thread per (b,k,l), 38 dot products over D=192, weights block-uniform.
// ---------------------------------------------------------------------------
__global__ __launch_bounds__(256) void k_proj(
    const float* __restrict__ x, const float* __restrict__ Wp,
    float* __restrict__ dtr, float* __restrict__ Bsv, float* __restrict__ Csv)
{
  const int tid = threadIdx.x;
  const int l = blockIdx.x * 256 + tid;
  const int k = blockIdx.y;
  const int b = blockIdx.z;
  const int pos = (k & 1) ? (((l & 63) << 6) | (l >> 6)) : l;
  const float* __restrict__ xrow = x + (size_t)b * DD * LL + pos;

  float acc[38];
#pragma unroll
  for (int c = 0; c < 38; ++c) acc[c] = 0.f;

  const float* __restrict__ wk = Wp + k * 38 * DD;

  float xn0 = xrow[0 * LL], xn1 = xrow[1 * LL], xn2 = xrow[2 * LL], xn3 = xrow[3 * LL];
  for (int d0 = 0; d0 < DD; d0 += 4) {
    const float x0 = xn0, x1 = xn1, x2 = xn2, x3 = xn3;
    if (d0 + 4 < DD) {
      xn0 = xrow[(size_t)(d0 + 4) * LL];
      xn1 = xrow[(size_t)(d0 + 5) * LL];
      xn2 = xrow[(size_t)(d0 + 6) * LL];
      xn3 = xrow[(size_t)(d0 + 7) * LL];
    }
#pragma unroll
    for (int c = 0; c < 38; ++c) {
      const float* __restrict__ wr = wk + c * DD + d0;
      float a = acc[c];
      a = fmaf(x0, wr[0], a);
      a = fmaf(x1, wr[1], a);
      a = fmaf(x2, wr[2], a);
      a = fmaf(x3, wr[3], a);
      acc[c] = a;
    }
  }

  const int ls = (k < 2) ? l : (LL - 1 - l);
  const size_t bk4 = (size_t)b * 4 + k;
  float* __restrict__ dr = dtr + (bk4 * LL + ls) * 8;
  *(float4*)(dr)     = make_float4(acc[0], acc[1], acc[2], acc[3]);
  *(float2*)(dr + 4) = make_float2(acc[4], acc[5]);
  float* __restrict__ br = Bsv + (bk4 * LL + ls) * NN;
  *(float4*)(br + 0)  = make_float4(acc[6],  acc[7],  acc[8],  acc[9]);
  *(float4*)(br + 4)  = make_float4(acc[10], acc[11], acc[12], acc[13]);
  *(float4*)(br + 8)  = make_float4(acc[14], acc[15], acc[16], acc[17]);
  *(float4*)(br + 12) = make_float4(acc[18], acc[19], acc[20], acc[21]);
  float* __restrict__ cr = Csv + (bk4 * LL + ls) * NN;
  *(float4*)(cr + 0)  = make_float4(acc[22], acc[23], acc[24], acc[25]);
  *(float4*)(cr + 4)  = make_float4(acc[26], acc[27], acc[28], acc[29]);
  *(float4*)(cr + 8)  = make_float4(acc[30], acc[31], acc[32], acc[33]);
  *(float4*)(cr + 12) = make_float4(acc[34], acc[35], acc[36], acc[37]);
}

// ---------------------------------------------------------------------------
// K2: tiled transpose x[b,d,p] -> xt[b,l,d] (row-major scan order) and
// xtt[b,l,d] (column-major scan order, l = sigma(p)), both bf16. 64x64 tiles
// through LDS (+1 pad). Makes every u-load in the scan a coalesced 384B row.
// ---------------------------------------------------------------------------
__global__ __launch_bounds__(256) void k_xt(
    const float* __restrict__ x, __hip_bfloat16* __restrict__ xt,
    __hip_bfloat16* __restrict__ xtt)
{
  __shared__ float tile[64][65];
  const int b = blockIdx.z, d0 = blockIdx.y * 64, p0 = blockIdx.x * 64;
  const int tx = threadIdx.x & 63, ty = threadIdx.x >> 6;
#pragma unroll
  for (int r = ty; r < 64; r += 4)
    tile[r][tx] = x[((size_t)b * DD + d0 + r) * LL + p0 + tx];
  __syncthreads();
#pragma unroll
  for (int pr = ty; pr < 64; pr += 4) {
    const int p = p0 + pr;
    const float vv = tile[tx][pr];
    const int l2 = ((p & 63) << 6) | (p >> 6);
    xt [((size_t)b * LL + p)  * DD + d0 + tx] = __float2bfloat16(vv);
    xtt[((size_t)b * LL + l2) * DD + d0 + tx] = __float2bfloat16(vv);
  }
}

// ---------------------------------------------------------------------------
// K3 (pass A): per-chunk scan summaries. One thread per (bk,d) chain, all 16
// states in registers -> zero cross-lane ops, ILP=16. Per step: broadcast
// dtr row (uniform -> s_load), broadcast B row, coalesced bf16 u row.
// P = prod(dA), q = local scan from h=0. Output bf16 [bk][c][d][n].
// ---------------------------------------------------------------------------
__global__ __launch_bounds__(192) void k_partial(
    const float* __restrict__ dtr, const float* __restrict__ Bsv,
    const __hip_bfloat16* __restrict__ xt, const __hip_bfloat16* __restrict__ xtt,
    const float* __restrict__ dtw, const float* __restrict__ dtb,
    const float* __restrict__ Alog,
    __hip_bfloat16* __restrict__ Pv, __hip_bfloat16* __restrict__ qv)
{
  const int d  = threadIdx.x;
  const int bk = blockIdx.x;
  const int c  = blockIdx.y;
  const int k = bk & 3, b = bk >> 2;
  const int kd = k * DD + d;

  float An[NN];
#pragma unroll
  for (int n = 0; n < NN; ++n) An[n] = -__expf(Alog[(size_t)kd * NN + n]);
  const float w0 = dtw[kd*6+0], w1 = dtw[kd*6+1], w2 = dtw[kd*6+2],
              w3 = dtw[kd*6+3], w4 = dtw[kd*6+4], w5 = dtw[kd*6+5];
  const float bias = dtb[kd];
  const bool rev = (k >= 2);
  const __hip_bfloat16* __restrict__ ub =
      ((k & 1) ? xtt : xt) + (size_t)b * LL * DD + d;
  const float* __restrict__ dtrp = dtr + (size_t)bk * LL * 8;
  const float* __restrict__ Bp   = Bsv + (size_t)bk * LL * NN;

  float P[NN], q[NN];
#pragma unroll
  for (int n = 0; n < NN; ++n) { P[n] = 1.f; q[n] = 0.f; }

#pragma unroll 2
  for (int i = 0; i < LC; ++i) {
    const int l = c * LC + i;
    const int row = rev ? (LL - 1 - l) : l;
    const float u = __bfloat162float(ub[(size_t)row * DD]);
    const float4 r0 = *(const float4*)(dtrp + (size_t)l * 8);
    const float2 r1 = *(const float2*)(dtrp + (size_t)l * 8 + 4);
    const float4 B0 = *(const float4*)(Bp + (size_t)l * NN);
    const float4 B1 = *(const float4*)(Bp + (size_t)l * NN + 4);
    const float4 B2 = *(const float4*)(Bp + (size_t)l * NN + 8);
    const float4 B3 = *(const float4*)(Bp + (size_t)l * NN + 12);
    float v = bias + r0.x*w0 + r0.y*w1 + r0.z*w2 + r0.w*w3 + r1.x*w4 + r1.y*w5;
    const float sp = (v > 20.f) ? v : __logf(1.f + __expf(v));
    const float dbu = sp * u;
    const float Bb[NN] = {B0.x,B0.y,B0.z,B0.w, B1.x,B1.y,B1.z,B1.w,
                          B2.x,B2.y,B2.z,B2.w, B3.x,B3.y,B3.z,B3.w};
#pragma unroll
    for (int n = 0; n < NN; ++n) {
      const float dA = __expf(sp * An[n]);
      P[n] *= dA;
      q[n] = fmaf(q[n], dA, dbu * Bb[n]);
    }
  }

  __hip_bfloat16* __restrict__ Pp = Pv + (((size_t)bk * NCH + c) * DD + d) * NN;
  __hip_bfloat16* __restrict__ qp = qv + (((size_t)bk * NCH + c) * DD + d) * NN;
#pragma unroll
  for (int n = 0; n < NN; ++n) {
    Pp[n] = __float2bfloat16(P[n]);
    qp[n] = __float2bfloat16(q[n]);
  }
}

// ---------------------------------------------------------------------------
// K4 (pass B): combine chunk summaries. One thread per (bk,d,n) = 98304.
// h_in[c] = h; h = P[c]*h + q[c], c ascending. Coalesced [bk][c][dn] walk.
// ---------------------------------------------------------------------------
__global__ __launch_bounds__(256) void k_comb(
    const __hip_bfloat16* __restrict__ Pv, const __hip_bfloat16* __restrict__ qv,
    __hip_bfloat16* __restrict__ hin)
{
  const int idx = blockIdx.x * 256 + threadIdx.x;
  const int dn = idx % (DD * NN);
  const int bk = idx / (DD * NN);
  const size_t base = (size_t)bk * NCH * DD * NN + dn;
  float h = 0.f;
  for (int c = 0; c < NCH; ++c) {
    const size_t a = base + (size_t)c * DD * NN;
    hin[a] = __float2bfloat16(h);
    h = fmaf(__bfloat162float(Pv[a]), h, __bfloat162float(qv[a]));
  }
}

// ---------------------------------------------------------------------------
// K5 (pass C): the real scan per chunk, seeded with h_in. Same structure as
// pass A plus C-row loads and y output. y is written at the OUTPUT position
// (reversal/transpose absorbed here) so the merge is 4 coalesced plane adds.
// ---------------------------------------------------------------------------
__global__ __launch_bounds__(192) void k_scanc(
    const float* __restrict__ dtr, const float* __restrict__ Bsv,
    const float* __restrict__ Csv,
    const __hip_bfloat16* __restrict__ xt, const __hip_bfloat16* __restrict__ xtt,
    const float* __restrict__ dtw, const float* __restrict__ dtb,
    const float* __restrict__ Alog, const __hip_bfloat16* __restrict__ hin,
    __hip_bfloat16* __restrict__ ys)
{
  const int d  = threadIdx.x;
  const int bk = blockIdx.x;
  const int c  = blockIdx.y;
  const int k = bk & 3, b = bk >> 2;
  const int kd = k * DD + d;

  float An[NN];
#pragma unroll
  for (int n = 0; n < NN; ++n) An[n] = -__expf(Alog[(size_t)kd * NN + n]);
  const float w0 = dtw[kd*6+0], w1 = dtw[kd*6+1], w2 = dtw[kd*6+2],
              w3 = dtw[kd*6+3], w4 = dtw[kd*6+4], w5 = dtw[kd*6+5];
  const float bias = dtb[kd];
  const bool rev = (k >= 2);
  const bool trans = (k & 1);
  const __hip_bfloat16* __restrict__ ub =
      (trans ? xtt : xt) + (size_t)b * LL * DD + d;
  const float* __restrict__ dtrp = dtr + (size_t)bk * LL * 8;
  const float* __restrict__ Bp   = Bsv + (size_t)bk * LL * NN;
  const float* __restrict__ Cp   = Csv + (size_t)bk * LL * NN;
  __hip_bfloat16* __restrict__ yp = ys + (size_t)bk * LL * DD + d;

  float h[NN];
  const __hip_bfloat16* __restrict__ hp = hin + (((size_t)bk * NCH + c) * DD + d) * NN;
#pragma unroll
  for (int n = 0; n < NN; ++n) h[n] = __bfloat162float(hp[n]);

#pragma unroll 2
  for (int i = 0; i < LC; ++i) {
    const int l = c * LC + i;
    const int base = rev ? (LL - 1 - l) : l;       // u row AND pre-transpose pos
    const float u = __bfloat162float(ub[(size_t)base * DD]);
    const float4 r0 = *(const float4*)(dtrp + (size_t)l * 8);
    const float2 r1 = *(const float2*)(dtrp + (size_t)l * 8 + 4);
    const float4 B0 = *(const float4*)(Bp + (size_t)l * NN);
    const float4 B1 = *(const float4*)(Bp + (size_t)l * NN + 4);
    const float4 B2 = *(const float4*)(Bp + (size_t)l * NN + 8);
    const float4 B3 = *(const float4*)(Bp + (size_t)l * NN + 12);
    const float4 C0 = *(const float4*)(Cp + (size_t)l * NN);
    const float4 C1 = *(const float4*)(Cp + (size_t)l * NN + 4);
    const float4 C2 = *(const float4*)(Cp + (size_t)l * NN + 8);
    const float4 C3 = *(const float4*)(Cp + (size_t)l * NN + 12);
    float v = bias + r0.x*w0 + r0.y*w1 + r0.z*w2 + r0.w*w3 + r1.x*w4 + r1.y*w5;
    const float sp = (v > 20.f) ? v : __logf(1.f + __expf(v));
    const float dbu = sp * u;
    const float Bb[NN] = {B0.x,B0.y,B0.z,B0.w, B1.x,B1.y,B1.z,B1.w,
                          B2.x,B2.y,B2.z,B2.w, B3.x,B3.y,B3.z,B3.w};
    const float Cb[NN] = {C0.x,C0.y,C0.z,C0.w, C1.x,C1.y,C1.z,C1.w,
                          C2.x,C2.y,C2.z,C2.w, C3.x,C3.y,C3.z,C3.w};
    float y0 = 0.f, y1 = 0.f, y2 = 0.f, y3 = 0.f;
#pragma unroll
    for (int n = 0; n < NN; n += 4) {
      float dA;
      dA = __expf(sp * An[n+0]); h[n+0] = fmaf(h[n+0], dA, dbu * Bb[n+0]); y0 = fmaf(h[n+0], Cb[n+0], y0);
      dA = __expf(sp * An[n+1]); h[n+1] = fmaf(h[n+1], dA, dbu * Bb[n+1]); y1 = fmaf(h[n+1], Cb[n+1], y1);
      dA = __expf(sp * An[n+2]); h[n+2] = fmaf(h[n+2], dA, dbu * Bb[n+2]); y2 = fmaf(h[n+2], Cb[n+2], y2);
      dA = __expf(sp * An[n+3]); h[n+3] = fmaf(h[n+3], dA, dbu * Bb[n+3]); y3 = fmaf(h[n+3], Cb[n+3], y3);
    }
    const float y = (y0 + y1) + (y2 + y3);
    const int pos = trans ? (((base & 63) << 6) | (base >> 6)) : base;
    yp[(size_t)pos * DD] = __float2bfloat16(y);
  }
}

// ---------------------------------------------------------------------------
// K6: merge + D-skip + LayerNorm(192) + channel-last store. ys planes are
// already output-positioned -> 4 coalesced reads at identical index. x-skip
// read fp32 via per-lane row float4 (exact). In-wave butterfly LN.
// ---------------------------------------------------------------------------
__global__ __launch_bounds__(64) void k_merge(
    const __hip_bfloat16* __restrict__ ys, const float* __restrict__ x,
    const float* __restrict__ Ds, const float* __restrict__ nw,
    const float* __restrict__ nb, float* __restrict__ out)
{
  const int lane = threadIdx.x;
  const int b = blockIdx.y;
  const int p0 = blockIdx.x * 16;

  float Dsum[3], nwv[3], nbv[3];
#pragma unroll
  for (int i = 0; i < 3; ++i) {
    int d = lane + 64 * i;
    Dsum[i] = Ds[d] + Ds[DD + d] + Ds[2 * DD + d] + Ds[3 * DD + d];
    nwv[i] = nw[d];
    nbv[i] = nb[d];
  }
  const __hip_bfloat16* __restrict__ ysb = ys + (size_t)b * 4 * LL * DD;
  const float* __restrict__ xb = x + (size_t)b * DD * LL;
  float* __restrict__ ob = out + (size_t)b * LL * DD;

  for (int chk = 0; chk < 2; ++chk) {
    const int q0 = p0 + chk * 8;
    float v[8][3];
    float xr[8][3];
#pragma unroll
    for (int i = 0; i < 3; ++i) {
      const float* __restrict__ xrow = xb + (size_t)(lane + 64 * i) * LL + q0;
      float4 x0 = *(const float4*)(xrow);
      float4 x1 = *(const float4*)(xrow + 4);
      xr[0][i]=x0.x; xr[1][i]=x0.y; xr[2][i]=x0.z; xr[3][i]=x0.w;
      xr[4][i]=x1.x; xr[5][i]=x1.y; xr[6][i]=x1.z; xr[7][i]=x1.w;
    }
#pragma unroll
    for (int j = 0; j < 8; ++j) {
      const int pos = q0 + j;
#pragma unroll
      for (int i = 0; i < 3; ++i) {
        const int d = lane + 64 * i;
        const size_t idx = (size_t)pos * DD + d;
        float s = __bfloat162float(ysb[idx])
                + __bfloat162float(ysb[(size_t)LL * DD + idx])
                + __bfloat162float(ysb[(size_t)2 * LL * DD + idx])
                + __bfloat162float(ysb[(size_t)3 * LL * DD + idx]);
        v[j][i] = s + xr[j][i] * Dsum[i];
      }
    }
#pragma unroll
    for (int j = 0; j < 8; ++j) {
      float s1 = v[j][0] + v[j][1] + v[j][2];
      float s2 = v[j][0]*v[j][0] + v[j][1]*v[j][1] + v[j][2]*v[j][2];
#pragma unroll
      for (int m = 1; m < 64; m <<= 1) {
        s1 += __shfl_xor(s1, m);
        s2 += __shfl_xor(s2, m);
      }
      const float mu  = s1 * (1.f / 192.f);
      const float var = s2 * (1.f / 192.f) - mu * mu;
      const float rs  = rsqrtf(var + 1e-5f);
      const int pos = q0 + j;
#pragma unroll
      for (int i = 0; i < 3; ++i) {
        ob[(size_t)pos * DD + lane + 64 * i] = (v[j][i] - mu) * rs * nwv[i] + nbv[i];
      }
    }
  }
}

// ---------------------------------------------------------------------------
// Workspace (fp32 slots), total 28,835,840 slots = 115.3 MB:
//   dtr  [32][4096][8]   fp32  @ 0          (1,048,576)
//   Bs   [32][4096][16]  fp32  @ 1,048,576  (2,097,152)
//   Cs   [32][4096][16]  fp32  @ 3,145,728  (2,097,152)
//   xt   [8][4096][192]  bf16  @ 5,242,880  (3,145,728 slots)
//   xtt  [8][4096][192]  bf16  @ 8,388,608  (3,145,728 slots)
//   ys   [32][4096][192] bf16  @ 11,534,336 (12,582,912 slots)
//   P    [32][32][192][16] bf16 @ 24,117,248 (1,572,864 slots)
//   q    same            bf16  @ 25,690,112 (1,572,864 slots)
//   hin  same            bf16  @ 27,262,976 (1,572,864 slots)
// ---------------------------------------------------------------------------
extern "C" void kernel_launch(void* const* d_in, const int* in_sizes, int n_in,
                              void* d_out, int out_size, void* d_ws, size_t ws_size,
                              hipStream_t stream)
{
  (void)in_sizes; (void)n_in; (void)out_size; (void)ws_size;
  const float* x    = (const float*)d_in[0];
  const float* Wp   = (const float*)d_in[1];
  const float* dtw  = (const float*)d_in[2];
  const float* dtb  = (const float*)d_in[3];
  const float* Alog = (const float*)d_in[4];
  const float* Ds   = (const float*)d_in[5];
  const float* nw   = (const float*)d_in[6];
  const float* nb   = (const float*)d_in[7];
  float* out = (float*)d_out;
  float* ws  = (float*)d_ws;

  float* dtrw = ws;
  float* Bsv  = ws + 1048576;
  float* Csv  = ws + 3145728;
  __hip_bfloat16* xt  = (__hip_bfloat16*)(ws + 5242880);
  __hip_bfloat16* xtt = (__hip_bfloat16*)(ws + 8388608);
  __hip_bfloat16* ysv = (__hip_bfloat16*)(ws + 11534336);
  __hip_bfloat16* Pv  = (__hip_bfloat16*)(ws + 24117248);
  __hip_bfloat16* qv  = (__hip_bfloat16*)(ws + 25690112);
  __hip_bfloat16* hiv = (__hip_bfloat16*)(ws + 27262976);

  k_proj   <<<dim3(16, 4, 8), 256, 0, stream>>>(x, Wp, dtrw, Bsv, Csv);
  k_xt     <<<dim3(64, 3, 8), 256, 0, stream>>>(x, xt, xtt);
  k_partial<<<dim3(32, NCH), DD, 0, stream>>>(dtrw, Bsv, xt, xtt, dtw, dtb, Alog, Pv, qv);
  k_comb   <<<384, 256, 0, stream>>>(Pv, qv, hiv);
  k_scanc  <<<dim3(32, NCH), DD, 0, stream>>>(dtrw, Bsv, Csv, xt, xtt, dtw, dtb, Alog, hiv, ysv);
  k_merge  <<<dim3(256, 8), 64, 0, stream>>>(ysv, x, Ds, nw, nb, out);
}

// Round 4
// 438.074 us; speedup vs baseline: 2.7659x; 1.1008x over previous
//
#include <hip/hip_runtime.h>
#include <hip/hip_bf16.h>

#define LL 4096
#define DD 192
#define NN 16
#define NCH 64      // chunks for the 2-pass scan
#define LC  64      // steps per chunk = LL/NCH

// ---------------------------------------------------------------------------
// K1: x_dbl projection, flat-position mapping. Thread owns flat pos p; x reads
// are coalesced for ALL k (xs[k] is a permutation of x). Write position:
//   k=0: p   k=1: sigma(p)   k=2: L-1-p   k=3: L-1-sigma(p)
// B/C rows are exactly one aligned 64B line -> scattered stores lose nothing.
// ---------------------------------------------------------------------------
__global__ __launch_bounds__(256) void k_proj(
    const float* __restrict__ x, const float* __restrict__ Wp,
    float* __restrict__ dtr, float* __restrict__ Bsv, float* __restrict__ Csv)
{
  const int tid = threadIdx.x;
  const int p = blockIdx.x * 256 + tid;
  const int k = blockIdx.y;
  const int b = blockIdx.z;
  const float* __restrict__ xrow = x + (size_t)b * DD * LL + p;

  float acc[38];
#pragma unroll
  for (int c = 0; c < 38; ++c) acc[c] = 0.f;

  const float* __restrict__ wk = Wp + k * 38 * DD;

  float xn0 = xrow[0 * LL], xn1 = xrow[1 * LL], xn2 = xrow[2 * LL], xn3 = xrow[3 * LL];
  for (int d0 = 0; d0 < DD; d0 += 4) {
    const float x0 = xn0, x1 = xn1, x2 = xn2, x3 = xn3;
    if (d0 + 4 < DD) {
      xn0 = xrow[(size_t)(d0 + 4) * LL];
      xn1 = xrow[(size_t)(d0 + 5) * LL];
      xn2 = xrow[(size_t)(d0 + 6) * LL];
      xn3 = xrow[(size_t)(d0 + 7) * LL];
    }
#pragma unroll
    for (int c = 0; c < 38; ++c) {
      const float* __restrict__ wr = wk + c * DD + d0;
      float a = acc[c];
      a = fmaf(x0, wr[0], a);
      a = fmaf(x1, wr[1], a);
      a = fmaf(x2, wr[2], a);
      a = fmaf(x3, wr[3], a);
      acc[c] = a;
    }
  }

  const int sp = ((p & 63) << 6) | (p >> 6);           // sigma(p), involution
  int ls;
  if      (k == 0) ls = p;
  else if (k == 1) ls = sp;
  else if (k == 2) ls = LL - 1 - p;
  else             ls = LL - 1 - sp;

  const size_t bk4 = (size_t)b * 4 + k;
  float* __restrict__ dr = dtr + (bk4 * LL + ls) * 8;   // 8-stride row, 6 used
  *(float4*)(dr)     = make_float4(acc[0], acc[1], acc[2], acc[3]);
  *(float2*)(dr + 4) = make_float2(acc[4], acc[5]);
  float* __restrict__ br = Bsv + (bk4 * LL + ls) * NN;
  *(float4*)(br + 0)  = make_float4(acc[6],  acc[7],  acc[8],  acc[9]);
  *(float4*)(br + 4)  = make_float4(acc[10], acc[11], acc[12], acc[13]);
  *(float4*)(br + 8)  = make_float4(acc[14], acc[15], acc[16], acc[17]);
  *(float4*)(br + 12) = make_float4(acc[18], acc[19], acc[20], acc[21]);
  float* __restrict__ cr = Csv + (bk4 * LL + ls) * NN;
  *(float4*)(cr + 0)  = make_float4(acc[22], acc[23], acc[24], acc[25]);
  *(float4*)(cr + 4)  = make_float4(acc[26], acc[27], acc[28], acc[29]);
  *(float4*)(cr + 8)  = make_float4(acc[30], acc[31], acc[32], acc[33]);
  *(float4*)(cr + 12) = make_float4(acc[34], acc[35], acc[36], acc[37]);
}

// ---------------------------------------------------------------------------
// K2: tiled transpose x[b,d,p] -> xt[b,p,d] bf16 (64x64 tiles through LDS).
// Scan kernels index rows of xt by any permutation — all threads of a block
// read the same row, so coalescing is row-index independent (xtt dropped).
// ---------------------------------------------------------------------------
__global__ __launch_bounds__(256) void k_xt(
    const float* __restrict__ x, __hip_bfloat16* __restrict__ xt)
{
  __shared__ float tile[64][65];
  const int b = blockIdx.z, d0 = blockIdx.y * 64, p0 = blockIdx.x * 64;
  const int tx = threadIdx.x & 63, ty = threadIdx.x >> 6;
#pragma unroll
  for (int r = ty; r < 64; r += 4)
    tile[r][tx] = x[((size_t)b * DD + d0 + r) * LL + p0 + tx];
  __syncthreads();
#pragma unroll
  for (int pr = ty; pr < 64; pr += 4)
    xt[((size_t)b * LL + p0 + pr) * DD + d0 + tx] = __float2bfloat16(tile[tx][pr]);
}

// u-row index for scan position l of direction k:
//   rl = rev ? L-1-l : l;  row = trans ? sigma(rl) : rl
__device__ __forceinline__ int urow(int l, bool rev, bool trans) {
  const int rl = rev ? (LL - 1 - l) : l;
  return trans ? (((rl & 63) << 6) | (rl >> 6)) : rl;
}

// ---------------------------------------------------------------------------
// K3 (pass A): per-chunk scan summaries. One thread per (bk,d) chain, 16
// states in registers, u prefetched one step ahead. P = prod(dA), q = local
// scan from h=0. Output bf16 [bk][c][d][n].
// ---------------------------------------------------------------------------
__global__ __launch_bounds__(192) void k_partial(
    const float* __restrict__ dtr, const float* __restrict__ Bsv,
    const __hip_bfloat16* __restrict__ xt,
    const float* __restrict__ dtw, const float* __restrict__ dtb,
    const float* __restrict__ Alog,
    __hip_bfloat16* __restrict__ Pv, __hip_bfloat16* __restrict__ qv)
{
  const int d  = threadIdx.x;
  const int bk = blockIdx.x;
  const int c  = blockIdx.y;
  const int k = bk & 3, b = bk >> 2;
  const int kd = k * DD + d;
  const bool rev = (k >= 2), trans = (k & 1);

  float An[NN];
#pragma unroll
  for (int n = 0; n < NN; ++n) An[n] = -__expf(Alog[(size_t)kd * NN + n]);
  const float w0 = dtw[kd*6+0], w1 = dtw[kd*6+1], w2 = dtw[kd*6+2],
              w3 = dtw[kd*6+3], w4 = dtw[kd*6+4], w5 = dtw[kd*6+5];
  const float bias = dtb[kd];
  const __hip_bfloat16* __restrict__ ub = xt + (size_t)b * LL * DD + d;
  const float* __restrict__ dtrp = dtr + (size_t)bk * LL * 8;
  const float* __restrict__ Bp   = Bsv + (size_t)bk * LL * NN;

  float P[NN], q[NN];
#pragma unroll
  for (int n = 0; n < NN; ++n) { P[n] = 1.f; q[n] = 0.f; }

  const int l0 = c * LC;
  float uc = __bfloat162float(ub[(size_t)urow(l0, rev, trans) * DD]);

#pragma unroll 2
  for (int i = 0; i < LC; ++i) {
    const int l = l0 + i;
    float un = 0.f;
    if (i + 1 < LC)
      un = __bfloat162float(ub[(size_t)urow(l + 1, rev, trans) * DD]);
    const float4 r0 = *(const float4*)(dtrp + (size_t)l * 8);
    const float2 r1 = *(const float2*)(dtrp + (size_t)l * 8 + 4);
    const float4 B0 = *(const float4*)(Bp + (size_t)l * NN);
    const float4 B1 = *(const float4*)(Bp + (size_t)l * NN + 4);
    const float4 B2 = *(const float4*)(Bp + (size_t)l * NN + 8);
    const float4 B3 = *(const float4*)(Bp + (size_t)l * NN + 12);
    float v = bias + r0.x*w0 + r0.y*w1 + r0.z*w2 + r0.w*w3 + r1.x*w4 + r1.y*w5;
    const float sp = (v > 20.f) ? v : __logf(1.f + __expf(v));
    const float dbu = sp * uc;
    const float Bb[NN] = {B0.x,B0.y,B0.z,B0.w, B1.x,B1.y,B1.z,B1.w,
                          B2.x,B2.y,B2.z,B2.w, B3.x,B3.y,B3.z,B3.w};
#pragma unroll
    for (int n = 0; n < NN; ++n) {
      const float dA = __expf(sp * An[n]);
      P[n] *= dA;
      q[n] = fmaf(q[n], dA, dbu * Bb[n]);
    }
    uc = un;
  }

  __hip_bfloat16* __restrict__ Pp = Pv + (((size_t)bk * NCH + c) * DD + d) * NN;
  __hip_bfloat16* __restrict__ qp = qv + (((size_t)bk * NCH + c) * DD + d) * NN;
#pragma unroll
  for (int n = 0; n < NN; ++n) {
    Pp[n] = __float2bfloat16(P[n]);
    qp[n] = __float2bfloat16(q[n]);
  }
}

// ---------------------------------------------------------------------------
// K4 (pass B): combine chunk summaries; h_in[c] overwrites P[c] IN PLACE
// (read P,q first, then store). One thread per (bk,d,n) = 98304.
// ---------------------------------------------------------------------------
__global__ __launch_bounds__(256) void k_comb(
    __hip_bfloat16* __restrict__ Pv, const __hip_bfloat16* __restrict__ qv)
{
  const int idx = blockIdx.x * 256 + threadIdx.x;
  const int dn = idx % (DD * NN);
  const int bk = idx / (DD * NN);
  const size_t base = (size_t)bk * NCH * DD * NN + dn;
  float h = 0.f;
  for (int c = 0; c < NCH; ++c) {
    const size_t a = base + (size_t)c * DD * NN;
    const float Pc = __bfloat162float(Pv[a]);
    const float qc = __bfloat162float(qv[a]);
    Pv[a] = __float2bfloat16(h);          // hin[c] = h (pre-chunk state)
    h = fmaf(Pc, h, qc);
  }
}

// ---------------------------------------------------------------------------
// K5 (pass C): real scan per chunk seeded with h_in (now living in Pv).
// y written at OUTPUT position (== u-row index) so merge is coalesced adds.
// ---------------------------------------------------------------------------
__global__ __launch_bounds__(192) void k_scanc(
    const float* __restrict__ dtr, const float* __restrict__ Bsv,
    const float* __restrict__ Csv, const __hip_bfloat16* __restrict__ xt,
    const float* __restrict__ dtw, const float* __restrict__ dtb,
    const float* __restrict__ Alog, const __hip_bfloat16* __restrict__ hin,
    __hip_bfloat16* __restrict__ ys)
{
  const int d  = threadIdx.x;
  const int bk = blockIdx.x;
  const int c  = blockIdx.y;
  const int k = bk & 3, b = bk >> 2;
  const int kd = k * DD + d;
  const bool rev = (k >= 2), trans = (k & 1);

  float An[NN];
#pragma unroll
  for (int n = 0; n < NN; ++n) An[n] = -__expf(Alog[(size_t)kd * NN + n]);
  const float w0 = dtw[kd*6+0], w1 = dtw[kd*6+1], w2 = dtw[kd*6+2],
              w3 = dtw[kd*6+3], w4 = dtw[kd*6+4], w5 = dtw[kd*6+5];
  const float bias = dtb[kd];
  const __hip_bfloat16* __restrict__ ub = xt + (size_t)b * LL * DD + d;
  const float* __restrict__ dtrp = dtr + (size_t)bk * LL * 8;
  const float* __restrict__ Bp   = Bsv + (size_t)bk * LL * NN;
  const float* __restrict__ Cp   = Csv + (size_t)bk * LL * NN;
  __hip_bfloat16* __restrict__ yp = ys + (size_t)bk * LL * DD + d;

  float h[NN];
  const __hip_bfloat16* __restrict__ hp = hin + (((size_t)bk * NCH + c) * DD + d) * NN;
#pragma unroll
  for (int n = 0; n < NN; ++n) h[n] = __bfloat162float(hp[n]);

  const int l0 = c * LC;
  int rowc = urow(l0, rev, trans);
  float uc = __bfloat162float(ub[(size_t)rowc * DD]);

#pragma unroll 2
  for (int i = 0; i < LC; ++i) {
    const int l = l0 + i;
    int rown = 0; float un = 0.f;
    if (i + 1 < LC) {
      rown = urow(l + 1, rev, trans);
      un = __bfloat162float(ub[(size_t)rown * DD]);
    }
    const float4 r0 = *(const float4*)(dtrp + (size_t)l * 8);
    const float2 r1 = *(const float2*)(dtrp + (size_t)l * 8 + 4);
    const float4 B0 = *(const float4*)(Bp + (size_t)l * NN);
    const float4 B1 = *(const float4*)(Bp + (size_t)l * NN + 4);
    const float4 B2 = *(const float4*)(Bp + (size_t)l * NN + 8);
    const float4 B3 = *(const float4*)(Bp + (size_t)l * NN + 12);
    const float4 C0 = *(const float4*)(Cp + (size_t)l * NN);
    const float4 C1 = *(const float4*)(Cp + (size_t)l * NN + 4);
    const float4 C2 = *(const float4*)(Cp + (size_t)l * NN + 8);
    const float4 C3 = *(const float4*)(Cp + (size_t)l * NN + 12);
    float v = bias + r0.x*w0 + r0.y*w1 + r0.z*w2 + r0.w*w3 + r1.x*w4 + r1.y*w5;
    const float sp = (v > 20.f) ? v : __logf(1.f + __expf(v));
    const float dbu = sp * uc;
    const float Bb[NN] = {B0.x,B0.y,B0.z,B0.w, B1.x,B1.y,B1.z,B1.w,
                          B2.x,B2.y,B2.z,B2.w, B3.x,B3.y,B3.z,B3.w};
    const float Cb[NN] = {C0.x,C0.y,C0.z,C0.w, C1.x,C1.y,C1.z,C1.w,
                          C2.x,C2.y,C2.z,C2.w, C3.x,C3.y,C3.z,C3.w};
    float y0 = 0.f, y1 = 0.f, y2 = 0.f, y3 = 0.f;
#pragma unroll
    for (int n = 0; n < NN; n += 4) {
      float dA;
      dA = __expf(sp * An[n+0]); h[n+0] = fmaf(h[n+0], dA, dbu * Bb[n+0]); y0 = fmaf(h[n+0], Cb[n+0], y0);
      dA = __expf(sp * An[n+1]); h[n+1] = fmaf(h[n+1], dA, dbu * Bb[n+1]); y1 = fmaf(h[n+1], Cb[n+1], y1);
      dA = __expf(sp * An[n+2]); h[n+2] = fmaf(h[n+2], dA, dbu * Bb[n+2]); y2 = fmaf(h[n+2], Cb[n+2], y2);
      dA = __expf(sp * An[n+3]); h[n+3] = fmaf(h[n+3], dA, dbu * Bb[n+3]); y3 = fmaf(h[n+3], Cb[n+3], y3);
    }
    yp[(size_t)rowc * DD] = __float2bfloat16((y0 + y1) + (y2 + y3));
    rowc = rown; uc = un;
  }
}

// ---------------------------------------------------------------------------
// K6: merge + D-skip + LayerNorm(192) + channel-last store (unchanged R3).
// ---------------------------------------------------------------------------
__global__ __launch_bounds__(64) void k_merge(
    const __hip_bfloat16* __restrict__ ys, const float* __restrict__ x,
    const float* __restrict__ Ds, const float* __restrict__ nw,
    const float* __restrict__ nb, float* __restrict__ out)
{
  const int lane = threadIdx.x;
  const int b = blockIdx.y;
  const int p0 = blockIdx.x * 16;

  float Dsum[3], nwv[3], nbv[3];
#pragma unroll
  for (int i = 0; i < 3; ++i) {
    int d = lane + 64 * i;
    Dsum[i] = Ds[d] + Ds[DD + d] + Ds[2 * DD + d] + Ds[3 * DD + d];
    nwv[i] = nw[d];
    nbv[i] = nb[d];
  }
  const __hip_bfloat16* __restrict__ ysb = ys + (size_t)b * 4 * LL * DD;
  const float* __restrict__ xb = x + (size_t)b * DD * LL;
  float* __restrict__ ob = out + (size_t)b * LL * DD;

  for (int chk = 0; chk < 2; ++chk) {
    const int q0 = p0 + chk * 8;
    float v[8][3];
    float xr[8][3];
#pragma unroll
    for (int i = 0; i < 3; ++i) {
      const float* __restrict__ xrow = xb + (size_t)(lane + 64 * i) * LL + q0;
      float4 x0 = *(const float4*)(xrow);
      float4 x1 = *(const float4*)(xrow + 4);
      xr[0][i]=x0.x; xr[1][i]=x0.y; xr[2][i]=x0.z; xr[3][i]=x0.w;
      xr[4][i]=x1.x; xr[5][i]=x1.y; xr[6][i]=x1.z; xr[7][i]=x1.w;
    }
#pragma unroll
    for (int j = 0; j < 8; ++j) {
      const int pos = q0 + j;
#pragma unroll
      for (int i = 0; i < 3; ++i) {
        const int d = lane + 64 * i;
        const size_t idx = (size_t)pos * DD + d;
        float s = __bfloat162float(ysb[idx])
                + __bfloat162float(ysb[(size_t)LL * DD + idx])
                + __bfloat162float(ysb[(size_t)2 * LL * DD + idx])
                + __bfloat162float(ysb[(size_t)3 * LL * DD + idx]);
        v[j][i] = s + xr[j][i] * Dsum[i];
      }
    }
#pragma unroll
    for (int j = 0; j < 8; ++j) {
      float s1 = v[j][0] + v[j][1] + v[j][2];
      float s2 = v[j][0]*v[j][0] + v[j][1]*v[j][1] + v[j][2]*v[j][2];
#pragma unroll
      for (int m = 1; m < 64; m <<= 1) {
        s1 += __shfl_xor(s1, m);
        s2 += __shfl_xor(s2, m);
      }
      const float mu  = s1 * (1.f / 192.f);
      const float var = s2 * (1.f / 192.f) - mu * mu;
      const float rs  = rsqrtf(var + 1e-5f);
      const int pos = q0 + j;
#pragma unroll
      for (int i = 0; i < 3; ++i) {
        ob[(size_t)pos * DD + lane + 64 * i] = (v[j][i] - mu) * rs * nwv[i] + nbv[i];
      }
    }
  }
}

// ---------------------------------------------------------------------------
// Workspace (fp32 slots), total 27,262,976 slots = 109.1 MB:
//   dtr [32][4096][8]    fp32 @ 0           (1,048,576)
//   Bs  [32][4096][16]   fp32 @ 1,048,576   (2,097,152)
//   Cs  [32][4096][16]   fp32 @ 3,145,728   (2,097,152)
//   xt  [8][4096][192]   bf16 @ 5,242,880   (3,145,728 slots)
//   ys  [32][4096][192]  bf16 @ 8,388,608   (12,582,912 slots)
//   P/hin [32][64][192][16] bf16 @ 20,971,520 (3,145,728 slots)
//   q   same             bf16 @ 24,117,248  (3,145,728 slots)
// ---------------------------------------------------------------------------
extern "C" void kernel_launch(void* const* d_in, const int* in_sizes, int n_in,
                              void* d_out, int out_size, void* d_ws, size_t ws_size,
                              hipStream_t stream)
{
  (void)in_sizes; (void)n_in; (void)out_size; (void)ws_size;
  const float* x    = (const float*)d_in[0];
  const float* Wp   = (const float*)d_in[1];
  const float* dtw  = (const float*)d_in[2];
  const float* dtb  = (const float*)d_in[3];
  const float* Alog = (const float*)d_in[4];
  const float* Ds   = (const float*)d_in[5];
  const float* nw   = (const float*)d_in[6];
  const float* nb   = (const float*)d_in[7];
  float* out = (float*)d_out;
  float* ws  = (float*)d_ws;

  float* dtrw = ws;
  float* Bsv  = ws + 1048576;
  float* Csv  = ws + 3145728;
  __hip_bfloat16* xt  = (__hip_bfloat16*)(ws + 5242880);
  __hip_bfloat16* ysv = (__hip_bfloat16*)(ws + 8388608);
  __hip_bfloat16* Pv  = (__hip_bfloat16*)(ws + 20971520);
  __hip_bfloat16* qv  = (__hip_bfloat16*)(ws + 24117248);

  k_proj   <<<dim3(16, 4, 8), 256, 0, stream>>>(x, Wp, dtrw, Bsv, Csv);
  k_xt     <<<dim3(64, 3, 8), 256, 0, stream>>>(x, xt);
  k_partial<<<dim3(32, NCH), DD, 0, stream>>>(dtrw, Bsv, xt, dtw, dtb, Alog, Pv, qv);
  k_comb   <<<384, 256, 0, stream>>>(Pv, qv);
  k_scanc  <<<dim3(32, NCH), DD, 0, stream>>>(dtrw, Bsv, Csv, xt, dtw, dtb, Alog, Pv, ysv);
  k_merge  <<<dim3(256, 8), 64, 0, stream>>>(ysv, x, Ds, nw, nb, out);
}

// Round 6
// 398.172 us; speedup vs baseline: 3.0431x; 1.1002x over previous
//
#include <hip/hip_runtime.h>
#include <hip/hip_bf16.h>

#define LL 4096
#define DD 192
#define NN 16
#define NCH 64      // chunks for the 2-pass scan
#define LC  64      // steps per chunk = LL/NCH

typedef float v2f __attribute__((ext_vector_type(2)));

__device__ __forceinline__ v2f v2(float a, float b) { v2f r; r.x = a; r.y = b; return r; }
__device__ __forceinline__ float fexp2(float x) { return __builtin_amdgcn_exp2f(x); }

// ---------------------------------------------------------------------------
// K1: x_dbl projection, flat-position mapping (unchanged from R4).
// ---------------------------------------------------------------------------
__global__ __launch_bounds__(256) void k_proj(
    const float* __restrict__ x, const float* __restrict__ Wp,
    float* __restrict__ dtr, float* __restrict__ Bsv, float* __restrict__ Csv)
{
  const int tid = threadIdx.x;
  const int p = blockIdx.x * 256 + tid;
  const int k = blockIdx.y;
  const int b = blockIdx.z;
  const float* __restrict__ xrow = x + (size_t)b * DD * LL + p;

  float acc[38];
#pragma unroll
  for (int c = 0; c < 38; ++c) acc[c] = 0.f;

  const float* __restrict__ wk = Wp + k * 38 * DD;

  float xn0 = xrow[0 * LL], xn1 = xrow[1 * LL], xn2 = xrow[2 * LL], xn3 = xrow[3 * LL];
  for (int d0 = 0; d0 < DD; d0 += 4) {
    const float x0 = xn0, x1 = xn1, x2 = xn2, x3 = xn3;
    if (d0 + 4 < DD) {
      xn0 = xrow[(size_t)(d0 + 4) * LL];
      xn1 = xrow[(size_t)(d0 + 5) * LL];
      xn2 = xrow[(size_t)(d0 + 6) * LL];
      xn3 = xrow[(size_t)(d0 + 7) * LL];
    }
#pragma unroll
    for (int c = 0; c < 38; ++c) {
      const float* __restrict__ wr = wk + c * DD + d0;
      float a = acc[c];
      a = fmaf(x0, wr[0], a);
      a = fmaf(x1, wr[1], a);
      a = fmaf(x2, wr[2], a);
      a = fmaf(x3, wr[3], a);
      acc[c] = a;
    }
  }

  const int sp = ((p & 63) << 6) | (p >> 6);           // sigma(p), involution
  int ls;
  if      (k == 0) ls = p;
  else if (k == 1) ls = sp;
  else if (k == 2) ls = LL - 1 - p;
  else             ls = LL - 1 - sp;

  const size_t bk4 = (size_t)b * 4 + k;
  float* __restrict__ dr = dtr + (bk4 * LL + ls) * 8;   // 8-stride row, 6 used
  *(float4*)(dr)     = make_float4(acc[0], acc[1], acc[2], acc[3]);
  *(float2*)(dr + 4) = make_float2(acc[4], acc[5]);
  float* __restrict__ br = Bsv + (bk4 * LL + ls) * NN;
  *(float4*)(br + 0)  = make_float4(acc[6],  acc[7],  acc[8],  acc[9]);
  *(float4*)(br + 4)  = make_float4(acc[10], acc[11], acc[12], acc[13]);
  *(float4*)(br + 8)  = make_float4(acc[14], acc[15], acc[16], acc[17]);
  *(float4*)(br + 12) = make_float4(acc[18], acc[19], acc[20], acc[21]);
  float* __restrict__ cr = Csv + (bk4 * LL + ls) * NN;
  *(float4*)(cr + 0)  = make_float4(acc[22], acc[23], acc[24], acc[25]);
  *(float4*)(cr + 4)  = make_float4(acc[26], acc[27], acc[28], acc[29]);
  *(float4*)(cr + 8)  = make_float4(acc[30], acc[31], acc[32], acc[33]);
  *(float4*)(cr + 12) = make_float4(acc[34], acc[35], acc[36], acc[37]);
}

// ---------------------------------------------------------------------------
// K2: tiled transpose x[b,d,p] -> xt[b,p,d] bf16 (unchanged from R4).
// ---------------------------------------------------------------------------
__global__ __launch_bounds__(256) void k_xt(
    const float* __restrict__ x, __hip_bfloat16* __restrict__ xt)
{
  __shared__ float tile[64][65];
  const int b = blockIdx.z, d0 = blockIdx.y * 64, p0 = blockIdx.x * 64;
  const int tx = threadIdx.x & 63, ty = threadIdx.x >> 6;
#pragma unroll
  for (int r = ty; r < 64; r += 4)
    tile[r][tx] = x[((size_t)b * DD + d0 + r) * LL + p0 + tx];
  __syncthreads();
#pragma unroll
  for (int pr = ty; pr < 64; pr += 4)
    xt[((size_t)b * LL + p0 + pr) * DD + d0 + tx] = __float2bfloat16(tile[tx][pr]);
}

// u-row index for scan position l of direction k.
__device__ __forceinline__ int urow(int l, bool rev, bool trans) {
  const int rl = rev ? (LL - 1 - l) : l;
  return trans ? (((rl & 63) << 6) | (rl >> 6)) : rl;
}

// ---------------------------------------------------------------------------
// K3 (pass A): per-chunk scan summaries. Packed fp32: 16 states as 8 float2,
// v_pk_fma/v_pk_mul for P/q updates; dA via exp2 with log2e prefolded into An.
// dtr/B rows are wave-uniform -> s_load path (VGPR stays low, 6 waves/SIMD).
// ---------------------------------------------------------------------------
__global__ __launch_bounds__(192) void k_partial(
    const float* __restrict__ dtr, const float* __restrict__ Bsv,
    const __hip_bfloat16* __restrict__ xt,
    const float* __restrict__ dtw, const float* __restrict__ dtb,
    const float* __restrict__ Alog,
    __hip_bfloat16* __restrict__ Pv, __hip_bfloat16* __restrict__ qv)
{
  const int d  = threadIdx.x;
  const int bk = blockIdx.x;
  const int c  = blockIdx.y;
  const int k = bk & 3, b = bk >> 2;
  const int kd = k * DD + d;
  const bool rev = (k >= 2), trans = (k & 1);
  const float L2E = 1.4426950408889634f;

  v2f An2[8];
#pragma unroll
  for (int j = 0; j < 8; ++j)
    An2[j] = v2(-__expf(Alog[(size_t)kd * NN + 2*j])     * L2E,
                -__expf(Alog[(size_t)kd * NN + 2*j + 1]) * L2E);
  const float w0 = dtw[kd*6+0], w1 = dtw[kd*6+1], w2 = dtw[kd*6+2],
              w3 = dtw[kd*6+3], w4 = dtw[kd*6+4], w5 = dtw[kd*6+5];
  const float bias = dtb[kd];
  const __hip_bfloat16* __restrict__ ub = xt + (size_t)b * LL * DD + d;
  const float* __restrict__ dtrp = dtr + (size_t)bk * LL * 8;
  const float* __restrict__ Bp   = Bsv + (size_t)bk * LL * NN;

  v2f P2[8], q2[8];
#pragma unroll
  for (int j = 0; j < 8; ++j) { P2[j] = v2(1.f, 1.f); q2[j] = v2(0.f, 0.f); }

  const int l0 = c * LC;
  float uc = __bfloat162float(ub[(size_t)urow(l0, rev, trans) * DD]);

#pragma unroll 2
  for (int i = 0; i < LC; ++i) {
    const int l = l0 + i;
    float un = 0.f;
    if (i + 1 < LC)
      un = __bfloat162float(ub[(size_t)urow(l + 1, rev, trans) * DD]);
    const float4 r0 = *(const float4*)(dtrp + (size_t)l * 8);
    const float2 r1 = *(const float2*)(dtrp + (size_t)l * 8 + 4);
    const float4 B0 = *(const float4*)(Bp + (size_t)l * NN);
    const float4 B1 = *(const float4*)(Bp + (size_t)l * NN + 4);
    const float4 B2 = *(const float4*)(Bp + (size_t)l * NN + 8);
    const float4 B3 = *(const float4*)(Bp + (size_t)l * NN + 12);
    float v = bias + r0.x*w0 + r0.y*w1 + r0.z*w2 + r0.w*w3 + r1.x*w4 + r1.y*w5;
    const float sp = (v > 20.f) ? v : __logf(1.f + __expf(v));
    const float dbu = sp * uc;
    const v2f sp2  = v2(sp, sp);
    const v2f dbu2 = v2(dbu, dbu);
    const v2f Bv[8] = { v2(B0.x,B0.y), v2(B0.z,B0.w), v2(B1.x,B1.y), v2(B1.z,B1.w),
                        v2(B2.x,B2.y), v2(B2.z,B2.w), v2(B3.x,B3.y), v2(B3.z,B3.w) };
#pragma unroll
    for (int j = 0; j < 8; ++j) {
      const v2f a = sp2 * An2[j];                 // v_pk_mul
      v2f e; e.x = fexp2(a.x); e.y = fexp2(a.y);
      P2[j] = P2[j] * e;                          // v_pk_mul
      q2[j] = __builtin_elementwise_fma(q2[j], e, dbu2 * Bv[j]);  // pk_mul+pk_fma
    }
    uc = un;
  }

  __hip_bfloat16* __restrict__ Pp = Pv + (((size_t)bk * NCH + c) * DD + d) * NN;
  __hip_bfloat16* __restrict__ qp = qv + (((size_t)bk * NCH + c) * DD + d) * NN;
#pragma unroll
  for (int j = 0; j < 8; ++j) {
    Pp[2*j]   = __float2bfloat16(P2[j].x);
    Pp[2*j+1] = __float2bfloat16(P2[j].y);
    qp[2*j]   = __float2bfloat16(q2[j].x);
    qp[2*j+1] = __float2bfloat16(q2[j].y);
  }
}

// ---------------------------------------------------------------------------
// K4 (pass B): combine chunk summaries; h_in[c] overwrites P[c] in place.
// ---------------------------------------------------------------------------
__global__ __launch_bounds__(256) void k_comb(
    __hip_bfloat16* __restrict__ Pv, const __hip_bfloat16* __restrict__ qv)
{
  const int idx = blockIdx.x * 256 + threadIdx.x;
  const int dn = idx % (DD * NN);
  const int bk = idx / (DD * NN);
  const size_t base = (size_t)bk * NCH * DD * NN + dn;
  float h = 0.f;
  for (int c = 0; c < NCH; ++c) {
    const size_t a = base + (size_t)c * DD * NN;
    const float Pc = __bfloat162float(Pv[a]);
    const float qc = __bfloat162float(qv[a]);
    Pv[a] = __float2bfloat16(h);          // hin[c] = h (pre-chunk state)
    h = fmaf(Pc, h, qc);
  }
}

// ---------------------------------------------------------------------------
// K5 (pass C): real scan per chunk seeded with h_in (lives in Pv). Packed
// fp32 states + exp2 like pass A; y accumulated in 4 float2 lanes.
// ---------------------------------------------------------------------------
__global__ __launch_bounds__(192) void k_scanc(
    const float* __restrict__ dtr, const float* __restrict__ Bsv,
    const float* __restrict__ Csv, const __hip_bfloat16* __restrict__ xt,
    const float* __restrict__ dtw, const float* __restrict__ dtb,
    const float* __restrict__ Alog, const __hip_bfloat16* __restrict__ hin,
    __hip_bfloat16* __restrict__ ys)
{
  const int d  = threadIdx.x;
  const int bk = blockIdx.x;
  const int c  = blockIdx.y;
  const int k = bk & 3, b = bk >> 2;
  const int kd = k * DD + d;
  const bool rev = (k >= 2), trans = (k & 1);
  const float L2E = 1.4426950408889634f;

  v2f An2[8];
#pragma unroll
  for (int j = 0; j < 8; ++j)
    An2[j] = v2(-__expf(Alog[(size_t)kd * NN + 2*j])     * L2E,
                -__expf(Alog[(size_t)kd * NN + 2*j + 1]) * L2E);
  const float w0 = dtw[kd*6+0], w1 = dtw[kd*6+1], w2 = dtw[kd*6+2],
              w3 = dtw[kd*6+3], w4 = dtw[kd*6+4], w5 = dtw[kd*6+5];
  const float bias = dtb[kd];
  const __hip_bfloat16* __restrict__ ub = xt + (size_t)b * LL * DD + d;
  const float* __restrict__ dtrp = dtr + (size_t)bk * LL * 8;
  const float* __restrict__ Bp   = Bsv + (size_t)bk * LL * NN;
  const float* __restrict__ Cp   = Csv + (size_t)bk * LL * NN;
  __hip_bfloat16* __restrict__ yp = ys + (size_t)bk * LL * DD + d;

  v2f h2[8];
  const __hip_bfloat16* __restrict__ hp = hin + (((size_t)bk * NCH + c) * DD + d) * NN;
#pragma unroll
  for (int j = 0; j < 8; ++j)
    h2[j] = v2(__bfloat162float(hp[2*j]), __bfloat162float(hp[2*j+1]));

  const int l0 = c * LC;
  int rowc = urow(l0, rev, trans);
  float uc = __bfloat162float(ub[(size_t)rowc * DD]);

#pragma unroll 2
  for (int i = 0; i < LC; ++i) {
    const int l = l0 + i;
    int rown = 0; float un = 0.f;
    if (i + 1 < LC) {
      rown = urow(l + 1, rev, trans);
      un = __bfloat162float(ub[(size_t)rown * DD]);
    }
    const float4 r0 = *(const float4*)(dtrp + (size_t)l * 8);
    const float2 r1 = *(const float2*)(dtrp + (size_t)l * 8 + 4);
    const float4 B0 = *(const float4*)(Bp + (size_t)l * NN);
    const float4 B1 = *(const float4*)(Bp + (size_t)l * NN + 4);
    const float4 B2 = *(const float4*)(Bp + (size_t)l * NN + 8);
    const float4 B3 = *(const float4*)(Bp + (size_t)l * NN + 12);
    const float4 C0 = *(const float4*)(Cp + (size_t)l * NN);
    const float4 C1 = *(const float4*)(Cp + (size_t)l * NN + 4);
    const float4 C2 = *(const float4*)(Cp + (size_t)l * NN + 8);
    const float4 C3 = *(const float4*)(Cp + (size_t)l * NN + 12);
    float v = bias + r0.x*w0 + r0.y*w1 + r0.z*w2 + r0.w*w3 + r1.x*w4 + r1.y*w5;
    const float sp = (v > 20.f) ? v : __logf(1.f + __expf(v));
    const float dbu = sp * uc;
    const v2f sp2  = v2(sp, sp);
    const v2f dbu2 = v2(dbu, dbu);
    const v2f Bv[8] = { v2(B0.x,B0.y), v2(B0.z,B0.w), v2(B1.x,B1.y), v2(B1.z,B1.w),
                        v2(B2.x,B2.y), v2(B2.z,B2.w), v2(B3.x,B3.y), v2(B3.z,B3.w) };
    const v2f Cv[8] = { v2(C0.x,C0.y), v2(C0.z,C0.w), v2(C1.x,C1.y), v2(C1.z,C1.w),
                        v2(C2.x,C2.y), v2(C2.z,C2.w), v2(C3.x,C3.y), v2(C3.z,C3.w) };
    v2f ya = v2(0.f, 0.f), yb = v2(0.f, 0.f), yc = v2(0.f, 0.f), yd = v2(0.f, 0.f);
#pragma unroll
    for (int j = 0; j < 8; ++j) {
      const v2f a = sp2 * An2[j];
      v2f e; e.x = fexp2(a.x); e.y = fexp2(a.y);
      h2[j] = __builtin_elementwise_fma(h2[j], e, dbu2 * Bv[j]);
      v2f& yacc = (j < 2) ? ya : (j < 4) ? yb : (j < 6) ? yc : yd;
      yacc = __builtin_elementwise_fma(h2[j], Cv[j], yacc);
    }
    const v2f ysum = (ya + yb) + (yc + yd);
    yp[(size_t)rowc * DD] = __float2bfloat16(ysum.x + ysum.y);
    rowc = rown; uc = un;
  }
}

// ---------------------------------------------------------------------------
// K6: merge + D-skip + LayerNorm(192) + channel-last store (unchanged R4).
// ---------------------------------------------------------------------------
__global__ __launch_bounds__(64) void k_merge(
    const __hip_bfloat16* __restrict__ ys, const float* __restrict__ x,
    const float* __restrict__ Ds, const float* __restrict__ nw,
    const float* __restrict__ nb, float* __restrict__ out)
{
  const int lane = threadIdx.x;
  const int b = blockIdx.y;
  const int p0 = blockIdx.x * 16;

  float Dsum[3], nwv[3], nbv[3];
#pragma unroll
  for (int i = 0; i < 3; ++i) {
    int d = lane + 64 * i;
    Dsum[i] = Ds[d] + Ds[DD + d] + Ds[2 * DD + d] + Ds[3 * DD + d];
    nwv[i] = nw[d];
    nbv[i] = nb[d];
  }
  const __hip_bfloat16* __restrict__ ysb = ys + (size_t)b * 4 * LL * DD;
  const float* __restrict__ xb = x + (size_t)b * DD * LL;
  float* __restrict__ ob = out + (size_t)b * LL * DD;

  for (int chk = 0; chk < 2; ++chk) {
    const int q0 = p0 + chk * 8;
    float v[8][3];
    float xr[8][3];
#pragma unroll
    for (int i = 0; i < 3; ++i) {
      const float* __restrict__ xrow = xb + (size_t)(lane + 64 * i) * LL + q0;
      float4 x0 = *(const float4*)(xrow);
      float4 x1 = *(const float4*)(xrow + 4);
      xr[0][i]=x0.x; xr[1][i]=x0.y; xr[2][i]=x0.z; xr[3][i]=x0.w;
      xr[4][i]=x1.x; xr[5][i]=x1.y; xr[6][i]=x1.z; xr[7][i]=x1.w;
    }
#pragma unroll
    for (int j = 0; j < 8; ++j) {
      const int pos = q0 + j;
#pragma unroll
      for (int i = 0; i < 3; ++i) {
        const int d = lane + 64 * i;
        const size_t idx = (size_t)pos * DD + d;
        float s = __bfloat162float(ysb[idx])
                + __bfloat162float(ysb[(size_t)LL * DD + idx])
                + __bfloat162float(ysb[(size_t)2 * LL * DD + idx])
                + __bfloat162float(ysb[(size_t)3 * LL * DD + idx]);
        v[j][i] = s + xr[j][i] * Dsum[i];
      }
    }
#pragma unroll
    for (int j = 0; j < 8; ++j) {
      float s1 = v[j][0] + v[j][1] + v[j][2];
      float s2 = v[j][0]*v[j][0] + v[j][1]*v[j][1] + v[j][2]*v[j][2];
#pragma unroll
      for (int m = 1; m < 64; m <<= 1) {
        s1 += __shfl_xor(s1, m);
        s2 += __shfl_xor(s2, m);
      }
      const float mu  = s1 * (1.f / 192.f);
      const float var = s2 * (1.f / 192.f) - mu * mu;
      const float rs  = rsqrtf(var + 1e-5f);
      const int pos = q0 + j;
#pragma unroll
      for (int i = 0; i < 3; ++i) {
        ob[(size_t)pos * DD + lane + 64 * i] = (v[j][i] - mu) * rs * nwv[i] + nbv[i];
      }
    }
  }
}

// ---------------------------------------------------------------------------
// Workspace (fp32 slots), total 27,262,976 slots = 109.1 MB (same as R4):
//   dtr [32][4096][8]    fp32 @ 0           (1,048,576)
//   Bs  [32][4096][16]   fp32 @ 1,048,576   (2,097,152)
//   Cs  [32][4096][16]   fp32 @ 3,145,728   (2,097,152)
//   xt  [8][4096][192]   bf16 @ 5,242,880   (3,145,728 slots)
//   ys  [32][4096][192]  bf16 @ 8,388,608   (12,582,912 slots)
//   P/hin [32][64][192][16] bf16 @ 20,971,520 (3,145,728 slots)
//   q   same             bf16 @ 24,117,248  (3,145,728 slots)
// ---------------------------------------------------------------------------
extern "C" void kernel_launch(void* const* d_in, const int* in_sizes, int n_in,
                              void* d_out, int out_size, void* d_ws, size_t ws_size,
                              hipStream_t stream)
{
  (void)in_sizes; (void)n_in; (void)out_size; (void)ws_size;
  const float* x    = (const float*)d_in[0];
  const float* Wp   = (const float*)d_in[1];
  const float* dtw  = (const float*)d_in[2];
  const float* dtb  = (const float*)d_in[3];
  const float* Alog = (const float*)d_in[4];
  const float* Ds   = (const float*)d_in[5];
  const float* nw   = (const float*)d_in[6];
  const float* nb   = (const float*)d_in[7];
  float* out = (float*)d_out;
  float* ws  = (float*)d_ws;

  float* dtrw = ws;
  float* Bsv  = ws + 1048576;
  float* Csv  = ws + 3145728;
  __hip_bfloat16* xt  = (__hip_bfloat16*)(ws + 5242880);
  __hip_bfloat16* ysv = (__hip_bfloat16*)(ws + 8388608);
  __hip_bfloat16* Pv  = (__hip_bfloat16*)(ws + 20971520);
  __hip_bfloat16* qv  = (__hip_bfloat16*)(ws + 24117248);

  k_proj   <<<dim3(16, 4, 8), 256, 0, stream>>>(x, Wp, dtrw, Bsv, Csv);
  k_xt     <<<dim3(64, 3, 8), 256, 0, stream>>>(x, xt);
  k_partial<<<dim3(32, NCH), DD, 0, stream>>>(dtrw, Bsv, xt, dtw, dtb, Alog, Pv, qv);
  k_comb   <<<384, 256, 0, stream>>>(Pv, qv);
  k_scanc  <<<dim3(32, NCH), DD, 0, stream>>>(dtrw, Bsv, Csv, xt, dtw, dtb, Alog, Pv, ysv);
  k_merge  <<<dim3(256, 8), 64, 0, stream>>>(ysv, x, Ds, nw, nb, out);
}

// Round 7
// 395.801 us; speedup vs baseline: 3.0614x; 1.0060x over previous
//
#include <hip/hip_runtime.h>
#include <hip/hip_bf16.h>

#define LL 4096
#define DD 192
#define NN 16
#define NCH 64      // chunks for the 2-pass scan
#define LC  64      // steps per chunk = LL/NCH

typedef float v2f __attribute__((ext_vector_type(2)));

__device__ __forceinline__ v2f v2(float a, float b) { v2f r; r.x = a; r.y = b; return r; }
__device__ __forceinline__ float fexp2(float x) { return __builtin_amdgcn_exp2f(x); }

// ---------------------------------------------------------------------------
// K1: x_dbl projection, flat-position mapping. launch_bounds(256,1): min
// 1 wave/EU -> full VGPR budget. acc[38] + pipelined weight loads need ~80
// VGPRs; the previous build reported VGPR_Count=32 => spill/remat disaster.
// ---------------------------------------------------------------------------
__global__ __launch_bounds__(256, 1) void k_proj(
    const float* __restrict__ x, const float* __restrict__ Wp,
    float* __restrict__ dtr, float* __restrict__ Bsv, float* __restrict__ Csv)
{
  const int tid = threadIdx.x;
  const int p = blockIdx.x * 256 + tid;
  const int k = blockIdx.y;
  const int b = blockIdx.z;
  const float* __restrict__ xrow = x + (size_t)b * DD * LL + p;

  float acc[38];
#pragma unroll
  for (int c = 0; c < 38; ++c) acc[c] = 0.f;

  const float* __restrict__ wk = Wp + k * 38 * DD;

  float xn0 = xrow[0 * LL], xn1 = xrow[1 * LL], xn2 = xrow[2 * LL], xn3 = xrow[3 * LL];
  for (int d0 = 0; d0 < DD; d0 += 4) {
    const float x0 = xn0, x1 = xn1, x2 = xn2, x3 = xn3;
    if (d0 + 4 < DD) {
      xn0 = xrow[(size_t)(d0 + 4) * LL];
      xn1 = xrow[(size_t)(d0 + 5) * LL];
      xn2 = xrow[(size_t)(d0 + 6) * LL];
      xn3 = xrow[(size_t)(d0 + 7) * LL];
    }
#pragma unroll
    for (int c = 0; c < 38; ++c) {
      const float* __restrict__ wr = wk + c * DD + d0;
      float a = acc[c];
      a = fmaf(x0, wr[0], a);
      a = fmaf(x1, wr[1], a);
      a = fmaf(x2, wr[2], a);
      a = fmaf(x3, wr[3], a);
      acc[c] = a;
    }
  }

  const int sp = ((p & 63) << 6) | (p >> 6);           // sigma(p), involution
  int ls;
  if      (k == 0) ls = p;
  else if (k == 1) ls = sp;
  else if (k == 2) ls = LL - 1 - p;
  else             ls = LL - 1 - sp;

  const size_t bk4 = (size_t)b * 4 + k;
  float* __restrict__ dr = dtr + (bk4 * LL + ls) * 8;   // 8-stride row, 6 used
  *(float4*)(dr)     = make_float4(acc[0], acc[1], acc[2], acc[3]);
  *(float2*)(dr + 4) = make_float2(acc[4], acc[5]);
  float* __restrict__ br = Bsv + (bk4 * LL + ls) * NN;
  *(float4*)(br + 0)  = make_float4(acc[6],  acc[7],  acc[8],  acc[9]);
  *(float4*)(br + 4)  = make_float4(acc[10], acc[11], acc[12], acc[13]);
  *(float4*)(br + 8)  = make_float4(acc[14], acc[15], acc[16], acc[17]);
  *(float4*)(br + 12) = make_float4(acc[18], acc[19], acc[20], acc[21]);
  float* __restrict__ cr = Csv + (bk4 * LL + ls) * NN;
  *(float4*)(cr + 0)  = make_float4(acc[22], acc[23], acc[24], acc[25]);
  *(float4*)(cr + 4)  = make_float4(acc[26], acc[27], acc[28], acc[29]);
  *(float4*)(cr + 8)  = make_float4(acc[30], acc[31], acc[32], acc[33]);
  *(float4*)(cr + 12) = make_float4(acc[34], acc[35], acc[36], acc[37]);
}

// ---------------------------------------------------------------------------
// K2: tiled transpose x[b,d,p] -> xt[b,p,d] bf16 (unchanged).
// ---------------------------------------------------------------------------
__global__ __launch_bounds__(256, 1) void k_xt(
    const float* __restrict__ x, __hip_bfloat16* __restrict__ xt)
{
  __shared__ float tile[64][65];
  const int b = blockIdx.z, d0 = blockIdx.y * 64, p0 = blockIdx.x * 64;
  const int tx = threadIdx.x & 63, ty = threadIdx.x >> 6;
#pragma unroll
  for (int r = ty; r < 64; r += 4)
    tile[r][tx] = x[((size_t)b * DD + d0 + r) * LL + p0 + tx];
  __syncthreads();
#pragma unroll
  for (int pr = ty; pr < 64; pr += 4)
    xt[((size_t)b * LL + p0 + pr) * DD + d0 + tx] = __float2bfloat16(tile[tx][pr]);
}

// u-row index for scan position l of direction k.
__device__ __forceinline__ int urow(int l, bool rev, bool trans) {
  const int rl = rev ? (LL - 1 - l) : l;
  return trans ? (((rl & 63) << 6) | (rl >> 6)) : rl;
}

// ---------------------------------------------------------------------------
// K3 (pass A): per-chunk scan summaries. Packed fp32 + exp2-prescaled A.
// launch_bounds(192,1): P2/q2/An2 = 48 VGPRs of live state; let them live.
// ---------------------------------------------------------------------------
__global__ __launch_bounds__(192, 1) void k_partial(
    const float* __restrict__ dtr, const float* __restrict__ Bsv,
    const __hip_bfloat16* __restrict__ xt,
    const float* __restrict__ dtw, const float* __restrict__ dtb,
    const float* __restrict__ Alog,
    __hip_bfloat16* __restrict__ Pv, __hip_bfloat16* __restrict__ qv)
{
  const int d  = threadIdx.x;
  const int bk = blockIdx.x;
  const int c  = blockIdx.y;
  const int k = bk & 3, b = bk >> 2;
  const int kd = k * DD + d;
  const bool rev = (k >= 2), trans = (k & 1);
  const float L2E = 1.4426950408889634f;

  v2f An2[8];
#pragma unroll
  for (int j = 0; j < 8; ++j)
    An2[j] = v2(-__expf(Alog[(size_t)kd * NN + 2*j])     * L2E,
                -__expf(Alog[(size_t)kd * NN + 2*j + 1]) * L2E);
  const float w0 = dtw[kd*6+0], w1 = dtw[kd*6+1], w2 = dtw[kd*6+2],
              w3 = dtw[kd*6+3], w4 = dtw[kd*6+4], w5 = dtw[kd*6+5];
  const float bias = dtb[kd];
  const __hip_bfloat16* __restrict__ ub = xt + (size_t)b * LL * DD + d;
  const float* __restrict__ dtrp = dtr + (size_t)bk * LL * 8;
  const float* __restrict__ Bp   = Bsv + (size_t)bk * LL * NN;

  v2f P2[8], q2[8];
#pragma unroll
  for (int j = 0; j < 8; ++j) { P2[j] = v2(1.f, 1.f); q2[j] = v2(0.f, 0.f); }

  const int l0 = c * LC;
  float uc = __bfloat162float(ub[(size_t)urow(l0, rev, trans) * DD]);

#pragma unroll 2
  for (int i = 0; i < LC; ++i) {
    const int l = l0 + i;
    float un = 0.f;
    if (i + 1 < LC)
      un = __bfloat162float(ub[(size_t)urow(l + 1, rev, trans) * DD]);
    const float4 r0 = *(const float4*)(dtrp + (size_t)l * 8);
    const float2 r1 = *(const float2*)(dtrp + (size_t)l * 8 + 4);
    const float4 B0 = *(const float4*)(Bp + (size_t)l * NN);
    const float4 B1 = *(const float4*)(Bp + (size_t)l * NN + 4);
    const float4 B2 = *(const float4*)(Bp + (size_t)l * NN + 8);
    const float4 B3 = *(const float4*)(Bp + (size_t)l * NN + 12);
    float v = bias + r0.x*w0 + r0.y*w1 + r0.z*w2 + r0.w*w3 + r1.x*w4 + r1.y*w5;
    const float sp = (v > 20.f) ? v : __logf(1.f + __expf(v));
    const float dbu = sp * uc;
    const v2f sp2  = v2(sp, sp);
    const v2f dbu2 = v2(dbu, dbu);
    const v2f Bv[8] = { v2(B0.x,B0.y), v2(B0.z,B0.w), v2(B1.x,B1.y), v2(B1.z,B1.w),
                        v2(B2.x,B2.y), v2(B2.z,B2.w), v2(B3.x,B3.y), v2(B3.z,B3.w) };
#pragma unroll
    for (int j = 0; j < 8; ++j) {
      const v2f a = sp2 * An2[j];                 // v_pk_mul
      v2f e; e.x = fexp2(a.x); e.y = fexp2(a.y);
      P2[j] = P2[j] * e;                          // v_pk_mul
      q2[j] = __builtin_elementwise_fma(q2[j], e, dbu2 * Bv[j]);  // pk_mul+pk_fma
    }
    uc = un;
  }

  __hip_bfloat16* __restrict__ Pp = Pv + (((size_t)bk * NCH + c) * DD + d) * NN;
  __hip_bfloat16* __restrict__ qp = qv + (((size_t)bk * NCH + c) * DD + d) * NN;
#pragma unroll
  for (int j = 0; j < 8; ++j) {
    Pp[2*j]   = __float2bfloat16(P2[j].x);
    Pp[2*j+1] = __float2bfloat16(P2[j].y);
    qp[2*j]   = __float2bfloat16(q2[j].x);
    qp[2*j+1] = __float2bfloat16(q2[j].y);
  }
}

// ---------------------------------------------------------------------------
// K4 (pass B): combine chunk summaries; h_in[c] overwrites P[c] in place.
// ---------------------------------------------------------------------------
__global__ __launch_bounds__(256, 1) void k_comb(
    __hip_bfloat16* __restrict__ Pv, const __hip_bfloat16* __restrict__ qv)
{
  const int idx = blockIdx.x * 256 + threadIdx.x;
  const int dn = idx % (DD * NN);
  const int bk = idx / (DD * NN);
  const size_t base = (size_t)bk * NCH * DD * NN + dn;
  float h = 0.f;
  for (int c = 0; c < NCH; ++c) {
    const size_t a = base + (size_t)c * DD * NN;
    const float Pc = __bfloat162float(Pv[a]);
    const float qc = __bfloat162float(qv[a]);
    Pv[a] = __float2bfloat16(h);          // hin[c] = h (pre-chunk state)
    h = fmaf(Pc, h, qc);
  }
}

// ---------------------------------------------------------------------------
// K5 (pass C): real scan per chunk seeded with h_in (lives in Pv). Packed
// fp32 states + exp2. launch_bounds(192,1): An2+h2 = 32 VGPRs live minimum.
// ---------------------------------------------------------------------------
__global__ __launch_bounds__(192, 1) void k_scanc(
    const float* __restrict__ dtr, const float* __restrict__ Bsv,
    const float* __restrict__ Csv, const __hip_bfloat16* __restrict__ xt,
    const float* __restrict__ dtw, const float* __restrict__ dtb,
    const float* __restrict__ Alog, const __hip_bfloat16* __restrict__ hin,
    __hip_bfloat16* __restrict__ ys)
{
  const int d  = threadIdx.x;
  const int bk = blockIdx.x;
  const int c  = blockIdx.y;
  const int k = bk & 3, b = bk >> 2;
  const int kd = k * DD + d;
  const bool rev = (k >= 2), trans = (k & 1);
  const float L2E = 1.4426950408889634f;

  v2f An2[8];
#pragma unroll
  for (int j = 0; j < 8; ++j)
    An2[j] = v2(-__expf(Alog[(size_t)kd * NN + 2*j])     * L2E,
                -__expf(Alog[(size_t)kd * NN + 2*j + 1]) * L2E);
  const float w0 = dtw[kd*6+0], w1 = dtw[kd*6+1], w2 = dtw[kd*6+2],
              w3 = dtw[kd*6+3], w4 = dtw[kd*6+4], w5 = dtw[kd*6+5];
  const float bias = dtb[kd];
  const __hip_bfloat16* __restrict__ ub = xt + (size_t)b * LL * DD + d;
  const float* __restrict__ dtrp = dtr + (size_t)bk * LL * 8;
  const float* __restrict__ Bp   = Bsv + (size_t)bk * LL * NN;
  const float* __restrict__ Cp   = Csv + (size_t)bk * LL * NN;
  __hip_bfloat16* __restrict__ yp = ys + (size_t)bk * LL * DD + d;

  v2f h2[8];
  const __hip_bfloat16* __restrict__ hp = hin + (((size_t)bk * NCH + c) * DD + d) * NN;
#pragma unroll
  for (int j = 0; j < 8; ++j)
    h2[j] = v2(__bfloat162float(hp[2*j]), __bfloat162float(hp[2*j+1]));

  const int l0 = c * LC;
  int rowc = urow(l0, rev, trans);
  float uc = __bfloat162float(ub[(size_t)rowc * DD]);

#pragma unroll 2
  for (int i = 0; i < LC; ++i) {
    const int l = l0 + i;
    int rown = 0; float un = 0.f;
    if (i + 1 < LC) {
      rown = urow(l + 1, rev, trans);
      un = __bfloat162float(ub[(size_t)rown * DD]);
    }
    const float4 r0 = *(const float4*)(dtrp + (size_t)l * 8);
    const float2 r1 = *(const float2*)(dtrp + (size_t)l * 8 + 4);
    const float4 B0 = *(const float4*)(Bp + (size_t)l * NN);
    const float4 B1 = *(const float4*)(Bp + (size_t)l * NN + 4);
    const float4 B2 = *(const float4*)(Bp + (size_t)l * NN + 8);
    const float4 B3 = *(const float4*)(Bp + (size_t)l * NN + 12);
    const float4 C0 = *(const float4*)(Cp + (size_t)l * NN);
    const float4 C1 = *(const float4*)(Cp + (size_t)l * NN + 4);
    const float4 C2 = *(const float4*)(Cp + (size_t)l * NN + 8);
    const float4 C3 = *(const float4*)(Cp + (size_t)l * NN + 12);
    float v = bias + r0.x*w0 + r0.y*w1 + r0.z*w2 + r0.w*w3 + r1.x*w4 + r1.y*w5;
    const float sp = (v > 20.f) ? v : __logf(1.f + __expf(v));
    const float dbu = sp * uc;
    const v2f sp2  = v2(sp, sp);
    const v2f dbu2 = v2(dbu, dbu);
    const v2f Bv[8] = { v2(B0.x,B0.y), v2(B0.z,B0.w), v2(B1.x,B1.y), v2(B1.z,B1.w),
                        v2(B2.x,B2.y), v2(B2.z,B2.w), v2(B3.x,B3.y), v2(B3.z,B3.w) };
    const v2f Cv[8] = { v2(C0.x,C0.y), v2(C0.z,C0.w), v2(C1.x,C1.y), v2(C1.z,C1.w),
                        v2(C2.x,C2.y), v2(C2.z,C2.w), v2(C3.x,C3.y), v2(C3.z,C3.w) };
    v2f ya = v2(0.f, 0.f), yb = v2(0.f, 0.f), yc = v2(0.f, 0.f), yd = v2(0.f, 0.f);
#pragma unroll
    for (int j = 0; j < 8; ++j) {
      const v2f a = sp2 * An2[j];
      v2f e; e.x = fexp2(a.x); e.y = fexp2(a.y);
      h2[j] = __builtin_elementwise_fma(h2[j], e, dbu2 * Bv[j]);
      v2f& yacc = (j < 2) ? ya : (j < 4) ? yb : (j < 6) ? yc : yd;
      yacc = __builtin_elementwise_fma(h2[j], Cv[j], yacc);
    }
    const v2f ysum = (ya + yb) + (yc + yd);
    yp[(size_t)rowc * DD] = __float2bfloat16(ysum.x + ysum.y);
    rowc = rown; uc = un;
  }
}

// ---------------------------------------------------------------------------
// K6: merge + D-skip + LayerNorm(192) + channel-last store. (64,1) bounds:
// v[8][3]+xr[8][3] = 48 live floats.
// ---------------------------------------------------------------------------
__global__ __launch_bounds__(64, 1) void k_merge(
    const __hip_bfloat16* __restrict__ ys, const float* __restrict__ x,
    const float* __restrict__ Ds, const float* __restrict__ nw,
    const float* __restrict__ nb, float* __restrict__ out)
{
  const int lane = threadIdx.x;
  const int b = blockIdx.y;
  const int p0 = blockIdx.x * 16;

  float Dsum[3], nwv[3], nbv[3];
#pragma unroll
  for (int i = 0; i < 3; ++i) {
    int d = lane + 64 * i;
    Dsum[i] = Ds[d] + Ds[DD + d] + Ds[2 * DD + d] + Ds[3 * DD + d];
    nwv[i] = nw[d];
    nbv[i] = nb[d];
  }
  const __hip_bfloat16* __restrict__ ysb = ys + (size_t)b * 4 * LL * DD;
  const float* __restrict__ xb = x + (size_t)b * DD * LL;
  float* __restrict__ ob = out + (size_t)b * LL * DD;

  for (int chk = 0; chk < 2; ++chk) {
    const int q0 = p0 + chk * 8;
    float v[8][3];
    float xr[8][3];
#pragma unroll
    for (int i = 0; i < 3; ++i) {
      const float* __restrict__ xrow = xb + (size_t)(lane + 64 * i) * LL + q0;
      float4 x0 = *(const float4*)(xrow);
      float4 x1 = *(const float4*)(xrow + 4);
      xr[0][i]=x0.x; xr[1][i]=x0.y; xr[2][i]=x0.z; xr[3][i]=x0.w;
      xr[4][i]=x1.x; xr[5][i]=x1.y; xr[6][i]=x1.z; xr[7][i]=x1.w;
    }
#pragma unroll
    for (int j = 0; j < 8; ++j) {
      const int pos = q0 + j;
#pragma unroll
      for (int i = 0; i < 3; ++i) {
        const int d = lane + 64 * i;
        const size_t idx = (size_t)pos * DD + d;
        float s = __bfloat162float(ysb[idx])
                + __bfloat162float(ysb[(size_t)LL * DD + idx])
                + __bfloat162float(ysb[(size_t)2 * LL * DD + idx])
                + __bfloat162float(ysb[(size_t)3 * LL * DD + idx]);
        v[j][i] = s + xr[j][i] * Dsum[i];
      }
    }
#pragma unroll
    for (int j = 0; j < 8; ++j) {
      float s1 = v[j][0] + v[j][1] + v[j][2];
      float s2 = v[j][0]*v[j][0] + v[j][1]*v[j][1] + v[j][2]*v[j][2];
#pragma unroll
      for (int m = 1; m < 64; m <<= 1) {
        s1 += __shfl_xor(s1, m);
        s2 += __shfl_xor(s2, m);
      }
      const float mu  = s1 * (1.f / 192.f);
      const float var = s2 * (1.f / 192.f) - mu * mu;
      const float rs  = rsqrtf(var + 1e-5f);
      const int pos = q0 + j;
#pragma unroll
      for (int i = 0; i < 3; ++i) {
        ob[(size_t)pos * DD + lane + 64 * i] = (v[j][i] - mu) * rs * nwv[i] + nbv[i];
      }
    }
  }
}

// ---------------------------------------------------------------------------
// Workspace (fp32 slots), total 27,262,976 slots = 109.1 MB (same as R6):
//   dtr [32][4096][8]    fp32 @ 0           (1,048,576)
//   Bs  [32][4096][16]   fp32 @ 1,048,576   (2,097,152)
//   Cs  [32][4096][16]   fp32 @ 3,145,728   (2,097,152)
//   xt  [8][4096][192]   bf16 @ 5,242,880   (3,145,728 slots)
//   ys  [32][4096][192]  bf16 @ 8,388,608   (12,582,912 slots)
//   P/hin [32][64][192][16] bf16 @ 20,971,520 (3,145,728 slots)
//   q   same             bf16 @ 24,117,248  (3,145,728 slots)
// ---------------------------------------------------------------------------
extern "C" void kernel_launch(void* const* d_in, const int* in_sizes, int n_in,
                              void* d_out, int out_size, void* d_ws, size_t ws_size,
                              hipStream_t stream)
{
  (void)in_sizes; (void)n_in; (void)out_size; (void)ws_size;
  const float* x    = (const float*)d_in[0];
  const float* Wp   = (const float*)d_in[1];
  const float* dtw  = (const float*)d_in[2];
  const float* dtb  = (const float*)d_in[3];
  const float* Alog = (const float*)d_in[4];
  const float* Ds   = (const float*)d_in[5];
  const float* nw   = (const float*)d_in[6];
  const float* nb   = (const float*)d_in[7];
  float* out = (float*)d_out;
  float* ws  = (float*)d_ws;

  float* dtrw = ws;
  float* Bsv  = ws + 1048576;
  float* Csv  = ws + 3145728;
  __hip_bfloat16* xt  = (__hip_bfloat16*)(ws + 5242880);
  __hip_bfloat16* ysv = (__hip_bfloat16*)(ws + 8388608);
  __hip_bfloat16* Pv  = (__hip_bfloat16*)(ws + 20971520);
  __hip_bfloat16* qv  = (__hip_bfloat16*)(ws + 24117248);

  k_proj   <<<dim3(16, 4, 8), 256, 0, stream>>>(x, Wp, dtrw, Bsv, Csv);
  k_xt     <<<dim3(64, 3, 8), 256, 0, stream>>>(x, xt);
  k_partial<<<dim3(32, NCH), DD, 0, stream>>>(dtrw, Bsv, xt, dtw, dtb, Alog, Pv, qv);
  k_comb   <<<384, 256, 0, stream>>>(Pv, qv);
  k_scanc  <<<dim3(32, NCH), DD, 0, stream>>>(dtrw, Bsv, Csv, xt, dtw, dtb, Alog, Pv, ysv);
  k_merge  <<<dim3(256, 8), 64, 0, stream>>>(ysv, x, Ds, nw, nb, out);
}

// Round 8
// 367.815 us; speedup vs baseline: 3.2943x; 1.0761x over previous
//
#include <hip/hip_runtime.h>
#include <hip/hip_bf16.h>

#define LL 4096
#define DD 192
#define NN 16
#define NCH 64      // chunks for the 2-pass scan
#define LC  64      // steps per chunk = LL/NCH

typedef float v2f __attribute__((ext_vector_type(2)));
typedef float f32x4 __attribute__((ext_vector_type(4)));
typedef short bf16x8 __attribute__((ext_vector_type(8)));   // 8 bf16 in 4 VGPRs

__device__ __forceinline__ v2f v2(float a, float b) { v2f r; r.x = a; r.y = b; return r; }
__device__ __forceinline__ float fexp2(float x) { return __builtin_amdgcn_exp2f(x); }

// ---------------------------------------------------------------------------
// K0: weight repack for the MFMA projection. Source Wp[k][38][192] fp32 ->
// packed [192][192] bf16 hi/lo pair. Packed row r: k=r/48, cc=r%48 with
//   cc 0..5  -> dt rows,  cc 8..23 -> B rows,  cc 24..39 -> C rows, rest 0.
// The 8/16/16 alignment makes every MFMA C-fragment float4 land inside one
// destination buffer row.
// ---------------------------------------------------------------------------
__global__ __launch_bounds__(192) void k_wprep(
    const float* __restrict__ Wp, __hip_bfloat16* __restrict__ Whi,
    __hip_bfloat16* __restrict__ Wlo)
{
  const int d = threadIdx.x;
  const int r = blockIdx.x;
  const int k = r / 48, cc = r % 48;
  float v = 0.f;
  if      (cc < 6)               v = Wp[((size_t)k * 38 + cc) * DD + d];
  else if (cc >= 8  && cc < 24)  v = Wp[((size_t)k * 38 + 6  + (cc - 8))  * DD + d];
  else if (cc >= 24 && cc < 40)  v = Wp[((size_t)k * 38 + 22 + (cc - 24)) * DD + d];
  const __hip_bfloat16 hi = __float2bfloat16(v);
  Whi[(size_t)r * DD + d] = hi;
  Wlo[(size_t)r * DD + d] = __float2bfloat16(v - __bfloat162float(hi));
}

// ---------------------------------------------------------------------------
// K2: tiled transpose x[b,d,p] -> xh[b,p,d] (bf16 hi) + xl (bf16 residual).
// xh doubles as the scan's u-source (same values as old xt).
// ---------------------------------------------------------------------------
__global__ __launch_bounds__(256) void k_xt(
    const float* __restrict__ x, __hip_bfloat16* __restrict__ xh,
    __hip_bfloat16* __restrict__ xl)
{
  __shared__ float tile[64][65];
  const int b = blockIdx.z, d0 = blockIdx.y * 64, p0 = blockIdx.x * 64;
  const int tx = threadIdx.x & 63, ty = threadIdx.x >> 6;
#pragma unroll
  for (int r = ty; r < 64; r += 4)
    tile[r][tx] = x[((size_t)b * DD + d0 + r) * LL + p0 + tx];
  __syncthreads();
#pragma unroll
  for (int pr = ty; pr < 64; pr += 4) {
    const float vv = tile[tx][pr];
    const __hip_bfloat16 hi = __float2bfloat16(vv);
    const size_t idx = ((size_t)b * LL + p0 + pr) * DD + d0 + tx;
    xh[idx] = hi;
    xl[idx] = __float2bfloat16(vv - __bfloat162float(hi));
  }
}

// ---------------------------------------------------------------------------
// K1 (new): MFMA projection. D[m=c_packed][n=p] = W[m][d] * xT[d][p], K=192
// as 6x mfma_f32_16x16x32_bf16, 3 hi/lo products for fp32-grade accuracy.
// Block = 3 waves; wave w owns M-tiles 4w..4w+3 (48 channels of 192);
// grid = (256 p-tiles, 8 b). A-frag: lane reads Whi[mt*16+(lane&15)]
// [ks*32+quad*8 ..+7] (16B row-contig). B-frag: xh[b][p0+(lane&15)]
// [ks*32+quad*8 ..+7]. C-frag: row=quad*4+reg=channel, col=lane&15=pos ->
// one float4 per (mt,lane) scattered to the scan-order dtr/Bs/Cs rows.
// ---------------------------------------------------------------------------
__global__ __launch_bounds__(192) void k_mfproj(
    const __hip_bfloat16* __restrict__ xh, const __hip_bfloat16* __restrict__ xl,
    const __hip_bfloat16* __restrict__ Whi, const __hip_bfloat16* __restrict__ Wlo,
    float* __restrict__ dtr, float* __restrict__ Bsv, float* __restrict__ Csv)
{
  const int tid  = threadIdx.x;
  const int w    = tid >> 6;          // wave 0..2
  const int lane = tid & 63;
  const int n    = lane & 15;
  const int quad = lane >> 4;
  const int p0   = blockIdx.x * 16;
  const int b    = blockIdx.y;
  const int p    = p0 + n;

  const short* __restrict__ xhp = (const short*)xh + ((size_t)b * LL + p) * DD + quad * 8;
  const short* __restrict__ xlp = (const short*)xl + ((size_t)b * LL + p) * DD + quad * 8;
  const short* __restrict__ whp = (const short*)Whi + ((size_t)(w * 4) * 16 + n) * DD + quad * 8;
  const short* __restrict__ wlp = (const short*)Wlo + ((size_t)(w * 4) * 16 + n) * DD + quad * 8;

  f32x4 acc[4];
#pragma unroll
  for (int m = 0; m < 4; ++m) acc[m] = (f32x4){0.f, 0.f, 0.f, 0.f};

#pragma unroll
  for (int ks = 0; ks < 6; ++ks) {
    const bf16x8 bh = *(const bf16x8*)(xhp + ks * 32);
    const bf16x8 bl = *(const bf16x8*)(xlp + ks * 32);
#pragma unroll
    for (int m = 0; m < 4; ++m) {
      const bf16x8 ah = *(const bf16x8*)(whp + (size_t)m * 16 * DD + ks * 32);
      const bf16x8 al = *(const bf16x8*)(wlp + (size_t)m * 16 * DD + ks * 32);
      acc[m] = __builtin_amdgcn_mfma_f32_16x16x32_bf16(ah, bh, acc[m], 0, 0, 0);
      acc[m] = __builtin_amdgcn_mfma_f32_16x16x32_bf16(ah, bl, acc[m], 0, 0, 0);
      acc[m] = __builtin_amdgcn_mfma_f32_16x16x32_bf16(al, bh, acc[m], 0, 0, 0);
    }
  }

  const int sg = ((p & 63) << 6) | (p >> 6);     // sigma(p)
  int lsv[4] = { p, sg, LL - 1 - p, LL - 1 - sg };

#pragma unroll
  for (int m = 0; m < 4; ++m) {
    const int mt = w * 4 + m;
    const int k  = mt / 3;                        // direction
    const int t  = mt - k * 3;                    // tile within direction
    const int cc0 = t * 16 + quad * 4;            // packed channel of reg 0
    const size_t rowb = (size_t)(b * 4 + k) * LL + lsv[k];
    const float4 vv = make_float4(acc[m][0], acc[m][1], acc[m][2], acc[m][3]);
    if      (cc0 < 8)  *(float4*)(dtr + rowb * 8  + cc0)        = vv;
    else if (cc0 < 24) *(float4*)(Bsv + rowb * 16 + (cc0 - 8))  = vv;
    else if (cc0 < 40) *(float4*)(Csv + rowb * 16 + (cc0 - 24)) = vv;
    // cc0 40/44: zero-pad rows, not stored
  }
}

// u-row index for scan position l of direction k.
__device__ __forceinline__ int urow(int l, bool rev, bool trans) {
  const int rl = rev ? (LL - 1 - l) : l;
  return trans ? (((rl & 63) << 6) | (rl >> 6)) : rl;
}

// ---------------------------------------------------------------------------
// K3 (pass A): per-chunk scan summaries (unchanged from R7).
// ---------------------------------------------------------------------------
__global__ __launch_bounds__(192) void k_partial(
    const float* __restrict__ dtr, const float* __restrict__ Bsv,
    const __hip_bfloat16* __restrict__ xt,
    const float* __restrict__ dtw, const float* __restrict__ dtb,
    const float* __restrict__ Alog,
    __hip_bfloat16* __restrict__ Pv, __hip_bfloat16* __restrict__ qv)
{
  const int d  = threadIdx.x;
  const int bk = blockIdx.x;
  const int c  = blockIdx.y;
  const int k = bk & 3, b = bk >> 2;
  const int kd = k * DD + d;
  const bool rev = (k >= 2), trans = (k & 1);
  const float L2E = 1.4426950408889634f;

  v2f An2[8];
#pragma unroll
  for (int j = 0; j < 8; ++j)
    An2[j] = v2(-__expf(Alog[(size_t)kd * NN + 2*j])     * L2E,
                -__expf(Alog[(size_t)kd * NN + 2*j + 1]) * L2E);
  const float w0 = dtw[kd*6+0], w1 = dtw[kd*6+1], w2 = dtw[kd*6+2],
              w3 = dtw[kd*6+3], w4 = dtw[kd*6+4], w5 = dtw[kd*6+5];
  const float bias = dtb[kd];
  const __hip_bfloat16* __restrict__ ub = xt + (size_t)b * LL * DD + d;
  const float* __restrict__ dtrp = dtr + (size_t)bk * LL * 8;
  const float* __restrict__ Bp   = Bsv + (size_t)bk * LL * NN;

  v2f P2[8], q2[8];
#pragma unroll
  for (int j = 0; j < 8; ++j) { P2[j] = v2(1.f, 1.f); q2[j] = v2(0.f, 0.f); }

  const int l0 = c * LC;
  float uc = __bfloat162float(ub[(size_t)urow(l0, rev, trans) * DD]);

#pragma unroll 2
  for (int i = 0; i < LC; ++i) {
    const int l = l0 + i;
    float un = 0.f;
    if (i + 1 < LC)
      un = __bfloat162float(ub[(size_t)urow(l + 1, rev, trans) * DD]);
    const float4 r0 = *(const float4*)(dtrp + (size_t)l * 8);
    const float2 r1 = *(const float2*)(dtrp + (size_t)l * 8 + 4);
    const float4 B0 = *(const float4*)(Bp + (size_t)l * NN);
    const float4 B1 = *(const float4*)(Bp + (size_t)l * NN + 4);
    const float4 B2 = *(const float4*)(Bp + (size_t)l * NN + 8);
    const float4 B3 = *(const float4*)(Bp + (size_t)l * NN + 12);
    float v = bias + r0.x*w0 + r0.y*w1 + r0.z*w2 + r0.w*w3 + r1.x*w4 + r1.y*w5;
    const float sp = (v > 20.f) ? v : __logf(1.f + __expf(v));
    const float dbu = sp * uc;
    const v2f sp2  = v2(sp, sp);
    const v2f dbu2 = v2(dbu, dbu);
    const v2f Bv[8] = { v2(B0.x,B0.y), v2(B0.z,B0.w), v2(B1.x,B1.y), v2(B1.z,B1.w),
                        v2(B2.x,B2.y), v2(B2.z,B2.w), v2(B3.x,B3.y), v2(B3.z,B3.w) };
#pragma unroll
    for (int j = 0; j < 8; ++j) {
      const v2f a = sp2 * An2[j];                 // v_pk_mul
      v2f e; e.x = fexp2(a.x); e.y = fexp2(a.y);
      P2[j] = P2[j] * e;                          // v_pk_mul
      q2[j] = __builtin_elementwise_fma(q2[j], e, dbu2 * Bv[j]);  // pk_mul+pk_fma
    }
    uc = un;
  }

  __hip_bfloat16* __restrict__ Pp = Pv + (((size_t)bk * NCH + c) * DD + d) * NN;
  __hip_bfloat16* __restrict__ qp = qv + (((size_t)bk * NCH + c) * DD + d) * NN;
#pragma unroll
  for (int j = 0; j < 8; ++j) {
    Pp[2*j]   = __float2bfloat16(P2[j].x);
    Pp[2*j+1] = __float2bfloat16(P2[j].y);
    qp[2*j]   = __float2bfloat16(q2[j].x);
    qp[2*j+1] = __float2bfloat16(q2[j].y);
  }
}

// ---------------------------------------------------------------------------
// K4 (pass B): combine chunk summaries; h_in[c] overwrites P[c] in place.
// ---------------------------------------------------------------------------
__global__ __launch_bounds__(256) void k_comb(
    __hip_bfloat16* __restrict__ Pv, const __hip_bfloat16* __restrict__ qv)
{
  const int idx = blockIdx.x * 256 + threadIdx.x;
  const int dn = idx % (DD * NN);
  const int bk = idx / (DD * NN);
  const size_t base = (size_t)bk * NCH * DD * NN + dn;
  float h = 0.f;
  for (int c = 0; c < NCH; ++c) {
    const size_t a = base + (size_t)c * DD * NN;
    const float Pc = __bfloat162float(Pv[a]);
    const float qc = __bfloat162float(qv[a]);
    Pv[a] = __float2bfloat16(h);          // hin[c] = h (pre-chunk state)
    h = fmaf(Pc, h, qc);
  }
}

// ---------------------------------------------------------------------------
// K5 (pass C): real scan per chunk seeded with h_in (unchanged from R7).
// ---------------------------------------------------------------------------
__global__ __launch_bounds__(192) void k_scanc(
    const float* __restrict__ dtr, const float* __restrict__ Bsv,
    const float* __restrict__ Csv, const __hip_bfloat16* __restrict__ xt,
    const float* __restrict__ dtw, const float* __restrict__ dtb,
    const float* __restrict__ Alog, const __hip_bfloat16* __restrict__ hin,
    __hip_bfloat16* __restrict__ ys)
{
  const int d  = threadIdx.x;
  const int bk = blockIdx.x;
  const int c  = blockIdx.y;
  const int k = bk & 3, b = bk >> 2;
  const int kd = k * DD + d;
  const bool rev = (k >= 2), trans = (k & 1);
  const float L2E = 1.4426950408889634f;

  v2f An2[8];
#pragma unroll
  for (int j = 0; j < 8; ++j)
    An2[j] = v2(-__expf(Alog[(size_t)kd * NN + 2*j])     * L2E,
                -__expf(Alog[(size_t)kd * NN + 2*j + 1]) * L2E);
  const float w0 = dtw[kd*6+0], w1 = dtw[kd*6+1], w2 = dtw[kd*6+2],
              w3 = dtw[kd*6+3], w4 = dtw[kd*6+4], w5 = dtw[kd*6+5];
  const float bias = dtb[kd];
  const __hip_bfloat16* __restrict__ ub = xt + (size_t)b * LL * DD + d;
  const float* __restrict__ dtrp = dtr + (size_t)bk * LL * 8;
  const float* __restrict__ Bp   = Bsv + (size_t)bk * LL * NN;
  const float* __restrict__ Cp   = Csv + (size_t)bk * LL * NN;
  __hip_bfloat16* __restrict__ yp = ys + (size_t)bk * LL * DD + d;

  v2f h2[8];
  const __hip_bfloat16* __restrict__ hp = hin + (((size_t)bk * NCH + c) * DD + d) * NN;
#pragma unroll
  for (int j = 0; j < 8; ++j)
    h2[j] = v2(__bfloat162float(hp[2*j]), __bfloat162float(hp[2*j+1]));

  const int l0 = c * LC;
  int rowc = urow(l0, rev, trans);
  float uc = __bfloat162float(ub[(size_t)rowc * DD]);

#pragma unroll 2
  for (int i = 0; i < LC; ++i) {
    const int l = l0 + i;
    int rown = 0; float un = 0.f;
    if (i + 1 < LC) {
      rown = urow(l + 1, rev, trans);
      un = __bfloat162float(ub[(size_t)rown * DD]);
    }
    const float4 r0 = *(const float4*)(dtrp + (size_t)l * 8);
    const float2 r1 = *(const float2*)(dtrp + (size_t)l * 8 + 4);
    const float4 B0 = *(const float4*)(Bp + (size_t)l * NN);
    const float4 B1 = *(const float4*)(Bp + (size_t)l * NN + 4);
    const float4 B2 = *(const float4*)(Bp + (size_t)l * NN + 8);
    const float4 B3 = *(const float4*)(Bp + (size_t)l * NN + 12);
    const float4 C0 = *(const float4*)(Cp + (size_t)l * NN);
    const float4 C1 = *(const float4*)(Cp + (size_t)l * NN + 4);
    const float4 C2 = *(const float4*)(Cp + (size_t)l * NN + 8);
    const float4 C3 = *(const float4*)(Cp + (size_t)l * NN + 12);
    float v = bias + r0.x*w0 + r0.y*w1 + r0.z*w2 + r0.w*w3 + r1.x*w4 + r1.y*w5;
    const float sp = (v > 20.f) ? v : __logf(1.f + __expf(v));
    const float dbu = sp * uc;
    const v2f sp2  = v2(sp, sp);
    const v2f dbu2 = v2(dbu, dbu);
    const v2f Bv[8] = { v2(B0.x,B0.y), v2(B0.z,B0.w), v2(B1.x,B1.y), v2(B1.z,B1.w),
                        v2(B2.x,B2.y), v2(B2.z,B2.w), v2(B3.x,B3.y), v2(B3.z,B3.w) };
    const v2f Cv[8] = { v2(C0.x,C0.y), v2(C0.z,C0.w), v2(C1.x,C1.y), v2(C1.z,C1.w),
                        v2(C2.x,C2.y), v2(C2.z,C2.w), v2(C3.x,C3.y), v2(C3.z,C3.w) };
    v2f ya = v2(0.f, 0.f), yb = v2(0.f, 0.f), yc = v2(0.f, 0.f), yd = v2(0.f, 0.f);
#pragma unroll
    for (int j = 0; j < 8; ++j) {
      const v2f a = sp2 * An2[j];
      v2f e; e.x = fexp2(a.x); e.y = fexp2(a.y);
      h2[j] = __builtin_elementwise_fma(h2[j], e, dbu2 * Bv[j]);
      v2f& yacc = (j < 2) ? ya : (j < 4) ? yb : (j < 6) ? yc : yd;
      yacc = __builtin_elementwise_fma(h2[j], Cv[j], yacc);
    }
    const v2f ysum = (ya + yb) + (yc + yd);
    yp[(size_t)rowc * DD] = __float2bfloat16(ysum.x + ysum.y);
    rowc = rown; uc = un;
  }
}

// ---------------------------------------------------------------------------
// K6: merge + D-skip + LayerNorm(192) + channel-last store (unchanged).
// ---------------------------------------------------------------------------
__global__ __launch_bounds__(64) void k_merge(
    const __hip_bfloat16* __restrict__ ys, const float* __restrict__ x,
    const float* __restrict__ Ds, const float* __restrict__ nw,
    const float* __restrict__ nb, float* __restrict__ out)
{
  const int lane = threadIdx.x;
  const int b = blockIdx.y;
  const int p0 = blockIdx.x * 16;

  float Dsum[3], nwv[3], nbv[3];
#pragma unroll
  for (int i = 0; i < 3; ++i) {
    int d = lane + 64 * i;
    Dsum[i] = Ds[d] + Ds[DD + d] + Ds[2 * DD + d] + Ds[3 * DD + d];
    nwv[i] = nw[d];
    nbv[i] = nb[d];
  }
  const __hip_bfloat16* __restrict__ ysb = ys + (size_t)b * 4 * LL * DD;
  const float* __restrict__ xb = x + (size_t)b * DD * LL;
  float* __restrict__ ob = out + (size_t)b * LL * DD;

  for (int chk = 0; chk < 2; ++chk) {
    const int q0 = p0 + chk * 8;
    float v[8][3];
    float xr[8][3];
#pragma unroll
    for (int i = 0; i < 3; ++i) {
      const float* __restrict__ xrow = xb + (size_t)(lane + 64 * i) * LL + q0;
      float4 x0 = *(const float4*)(xrow);
      float4 x1 = *(const float4*)(xrow + 4);
      xr[0][i]=x0.x; xr[1][i]=x0.y; xr[2][i]=x0.z; xr[3][i]=x0.w;
      xr[4][i]=x1.x; xr[5][i]=x1.y; xr[6][i]=x1.z; xr[7][i]=x1.w;
    }
#pragma unroll
    for (int j = 0; j < 8; ++j) {
      const int pos = q0 + j;
#pragma unroll
      for (int i = 0; i < 3; ++i) {
        const int d = lane + 64 * i;
        const size_t idx = (size_t)pos * DD + d;
        float s = __bfloat162float(ysb[idx])
                + __bfloat162float(ysb[(size_t)LL * DD + idx])
                + __bfloat162float(ysb[(size_t)2 * LL * DD + idx])
                + __bfloat162float(ysb[(size_t)3 * LL * DD + idx]);
        v[j][i] = s + xr[j][i] * Dsum[i];
      }
    }
#pragma unroll
    for (int j = 0; j < 8; ++j) {
      float s1 = v[j][0] + v[j][1] + v[j][2];
      float s2 = v[j][0]*v[j][0] + v[j][1]*v[j][1] + v[j][2]*v[j][2];
#pragma unroll
      for (int m = 1; m < 64; m <<= 1) {
        s1 += __shfl_xor(s1, m);
        s2 += __shfl_xor(s2, m);
      }
      const float mu  = s1 * (1.f / 192.f);
      const float var = s2 * (1.f / 192.f) - mu * mu;
      const float rs  = rsqrtf(var + 1e-5f);
      const int pos = q0 + j;
#pragma unroll
      for (int i = 0; i < 3; ++i) {
        ob[(size_t)pos * DD + lane + 64 * i] = (v[j][i] - mu) * rs * nwv[i] + nbv[i];
      }
    }
  }
}

// ---------------------------------------------------------------------------
// Workspace (fp32 slots), total 30,445,568 slots = 121.8 MB:
//   dtr [32][4096][8]    fp32 @ 0           (1,048,576)
//   Bs  [32][4096][16]   fp32 @ 1,048,576   (2,097,152)
//   Cs  [32][4096][16]   fp32 @ 3,145,728   (2,097,152)
//   xh  [8][4096][192]   bf16 @ 5,242,880   (3,145,728 slots)
//   ys  [32][4096][192]  bf16 @ 8,388,608   (12,582,912 slots)
//   P/hin [32][64][192][16] bf16 @ 20,971,520 (3,145,728 slots)
//   q   same             bf16 @ 24,117,248  (3,145,728 slots)
//   xl  [8][4096][192]   bf16 @ 27,262,976  (3,145,728 slots)
//   Whi [192][192]       bf16 @ 30,408,704  (18,432 slots)
//   Wlo [192][192]       bf16 @ 30,427,136  (18,432 slots)
// ---------------------------------------------------------------------------
extern "C" void kernel_launch(void* const* d_in, const int* in_sizes, int n_in,
                              void* d_out, int out_size, void* d_ws, size_t ws_size,
                              hipStream_t stream)
{
  (void)in_sizes; (void)n_in; (void)out_size; (void)ws_size;
  const float* x    = (const float*)d_in[0];
  const float* Wp   = (const float*)d_in[1];
  const float* dtw  = (const float*)d_in[2];
  const float* dtb  = (const float*)d_in[3];
  const float* Alog = (const float*)d_in[4];
  const float* Ds   = (const float*)d_in[5];
  const float* nw   = (const float*)d_in[6];
  const float* nb   = (const float*)d_in[7];
  float* out = (float*)d_out;
  float* ws  = (float*)d_ws;

  float* dtrw = ws;
  float* Bsv  = ws + 1048576;
  float* Csv  = ws + 3145728;
  __hip_bfloat16* xh  = (__hip_bfloat16*)(ws + 5242880);
  __hip_bfloat16* ysv = (__hip_bfloat16*)(ws + 8388608);
  __hip_bfloat16* Pv  = (__hip_bfloat16*)(ws + 20971520);
  __hip_bfloat16* qv  = (__hip_bfloat16*)(ws + 24117248);
  __hip_bfloat16* xlv = (__hip_bfloat16*)(ws + 27262976);
  __hip_bfloat16* Whi = (__hip_bfloat16*)(ws + 30408704);
  __hip_bfloat16* Wlo = (__hip_bfloat16*)(ws + 30427136);

  k_wprep  <<<192, 192, 0, stream>>>(Wp, Whi, Wlo);
  k_xt     <<<dim3(64, 3, 8), 256, 0, stream>>>(x, xh, xlv);
  k_mfproj <<<dim3(256, 8), 192, 0, stream>>>(xh, xlv, Whi, Wlo, dtrw, Bsv, Csv);
  k_partial<<<dim3(32, NCH), DD, 0, stream>>>(dtrw, Bsv, xh, dtw, dtb, Alog, Pv, qv);
  k_comb   <<<384, 256, 0, stream>>>(Pv, qv);
  k_scanc  <<<dim3(32, NCH), DD, 0, stream>>>(dtrw, Bsv, Csv, xh, dtw, dtb, Alog, Pv, ysv);
  k_merge  <<<dim3(256, 8), 64, 0, stream>>>(ysv, x, Ds, nw, nb, out);
}